// Round 4
// baseline (17168.340 us; speedup 1.0000x reference)
//
#include <hip/hip_runtime.h>

#define NBLK 256

// workspace layout (floats)
#define OFF_G    0            // 1024*1024
#define OFF_QT   1048576      // 128*1024
#define OFF_YS   1179648      // 4 slabs * 128*1024
#define OFF_CS   1703936      // 8 slabs * 128*128
#define OFF_LT   1835008      // 128*128
#define OFF_RP   1851392      // 16*1024
#define OFF_ACC  1867776      // 4 floats: match, range, trB, normR
#define OFF_BAR  1867780      // 2 uints: cnt, gen

union Smem {
    struct { float As[128][68]; float Bs[128][68]; } syrk;        // 69632 B
    struct { float Cs[128][129]; float inv_d[16]; } chol;         // 66112 B
    struct { float Ls[128 * 128]; float Xs[16][32]; } trsm;       // 67584 B
    struct { float As[32][68]; float Bs[32][68]; float Rs[64][16]; } gg;
    struct { float Ri[1024]; float red[256]; float As[32][68]; float Bs[32][68]; } gy;
    float red[256];
};

__device__ __forceinline__ void gridbar(unsigned* cnt, unsigned* gen) {
    __syncthreads();
    if (threadIdx.x == 0) {
        unsigned g = __hip_atomic_load(gen, __ATOMIC_RELAXED, __HIP_MEMORY_SCOPE_AGENT);
        unsigned v = __hip_atomic_fetch_add(cnt, 1u, __ATOMIC_ACQ_REL, __HIP_MEMORY_SCOPE_AGENT);
        if (v == NBLK - 1) {
            __hip_atomic_store(cnt, 0u, __ATOMIC_RELAXED, __HIP_MEMORY_SCOPE_AGENT);
            __hip_atomic_fetch_add(gen, 1u, __ATOMIC_RELEASE, __HIP_MEMORY_SCOPE_AGENT);
        } else {
            while (__hip_atomic_load(gen, __ATOMIC_RELAXED, __HIP_MEMORY_SCOPE_AGENT) == g)
                __builtin_amdgcn_s_sleep(2);
            (void)__hip_atomic_load(gen, __ATOMIC_ACQUIRE, __HIP_MEMORY_SCOPE_AGENT);
        }
    }
    __syncthreads();
}

__device__ __forceinline__ void dev_match(Smem* sm, const float* t1, const float* t2,
                                          float* accb, int w) {
    int tid = threadIdx.x;
    const float4* a = (const float4*)t1;
    const float4* b = (const float4*)t2;
    float s = 0.f;
    for (int i = w * 256 + tid; i < 1048576; i += 218 * 256) {
        float4 x = a[i], y = b[i];
        float d0 = x.x - y.x, d1 = x.y - y.y, d2 = x.z - y.z, d3 = x.w - y.w;
        s += d0 * d0 + d1 * d1 + d2 * d2 + d3 * d3;
    }
    sm->red[tid] = s; __syncthreads();
    for (int w2 = 128; w2 > 0; w2 >>= 1) {
        if (tid < w2) sm->red[tid] += sm->red[tid + w2];
        __syncthreads();
    }
    if (tid == 0) atomicAdd(&accb[0], sm->red[0]);
}

__device__ __forceinline__ void dev_range(Smem* sm, const float* params, const float* tmin,
                                          const float* tmax, float* accb) {
    int tid = threadIdx.x;
    float a = tmin[0], b = tmax[0];
    const float d = 0.01f;
    float s = 0.f;
    for (int i = tid; i < 128 * 17; i += 256) {
        float p = params[i];
        float r1 = (p - a - d) / (-d);
        float r2 = (p - b + d) / d;
        s += fmaxf(fmaxf(r1, r2), 0.f);
    }
    sm->red[tid] = s; __syncthreads();
    for (int w = 128; w > 0; w >>= 1) {
        if (tid < w) sm->red[tid] += sm->red[tid + w];
        __syncthreads();
    }
    if (tid == 0) atomicAdd(&accb[1], sm->red[0]);
}

__device__ __forceinline__ void dev_sumsq(Smem* sm, const float* X, float* accb, int w) {
    int tid = threadIdx.x;
    float s = 0.f;
    for (int i = w * 256 + tid; i < 131072; i += 1024) { float v = X[i]; s += v * v; }
    sm->red[tid] = s; __syncthreads();
    for (int w2 = 128; w2 > 0; w2 >>= 1) {
        if (tid < w2) sm->red[tid] += sm->red[tid + w2];
        __syncthreads();
    }
    if (tid == 0) atomicAdd(&accb[3], sm->red[0]);
}

// Cslab[z] = A_eff(64 rows p0) x B_eff(64 rows q0) over K-chunk z of 128
__device__ __forceinline__ void dev_syrk(Smem* sm, const float* A, int nsA,
                                         const float* B, int nsB, float* Cslab, int bid) {
    int tid = threadIdx.x;
    int q0 = (bid & 1) * 64, p0 = ((bid >> 1) & 1) * 64, z = bid >> 2;
    int kc = z * 128;
    for (int i = tid; i < 8192; i += 256) {
        int r = i >> 7, c = i & 127;
        float s = 0.f;
        for (int zz = 0; zz < nsA; ++zz) s += A[zz * 131072 + (p0 + r) * 1024 + kc + c];
        sm->syrk.As[c][r] = s;
    }
    for (int i = tid; i < 8192; i += 256) {
        int r = i >> 7, c = i & 127;
        float s = 0.f;
        for (int zz = 0; zz < nsB; ++zz) s += B[zz * 131072 + (q0 + r) * 1024 + kc + c];
        sm->syrk.Bs[c][r] = s;
    }
    __syncthreads();
    int tx = tid & 15, ty = tid >> 4;
    float acc[4][4] = {};
    for (int k = 0; k < 128; ++k) {
        float4 av = *(const float4*)&sm->syrk.As[k][ty * 4];
        float4 bv = *(const float4*)&sm->syrk.Bs[k][tx * 4];
        float a[4] = {av.x, av.y, av.z, av.w};
        float b[4] = {bv.x, bv.y, bv.z, bv.w};
        #pragma unroll
        for (int i = 0; i < 4; ++i)
            #pragma unroll
            for (int j = 0; j < 4; ++j) acc[i][j] += a[i] * b[j];
    }
    float* outp = &Cslab[z * 16384];
    for (int i = 0; i < 4; ++i)
        *(float4*)&outp[(p0 + ty * 4 + i) * 128 + q0 + tx * 4] =
            make_float4(acc[i][0], acc[i][1], acc[i][2], acc[i][3]);
}

// Blocked Cholesky; panel in one wave's registers (shfl), rank-16 trailing update.
// Lt[k*128+i] = L[i][k] for i>k; diag holds 1/L[k][k]; 0 above.
__device__ __forceinline__ void dev_chol(Smem* sm, const float* Cslab, float* Lt) {
    int tid = threadIdx.x;
    for (int f = tid; f < 128 * 128; f += 256) {
        float s = 0.f;
        #pragma unroll
        for (int z = 0; z < 8; ++z) s += Cslab[z * 16384 + f];
        sm->chol.Cs[f >> 7][f & 127] = s;
    }
    __syncthreads();
    int lane = tid & 63;
    for (int kb = 0; kb < 8; ++kb) {
        int k0 = kb * 16;
        if (tid < 64) {
            float P0[16], P1[16], invs[16];
            #pragma unroll
            for (int u = 0; u < 16; ++u) {
                P0[u] = sm->chol.Cs[lane][k0 + u];
                P1[u] = sm->chol.Cs[lane + 64][k0 + u];
            }
            #pragma unroll
            for (int kk = 0; kk < 16; ++kk) {
                int k = k0 + kk;
                int src = k & 63;
                bool hi = (k >= 64);
                float pr[16];
                #pragma unroll
                for (int u = 0; u < 16; ++u)
                    if (u >= kk) pr[u] = __shfl(hi ? P1[u] : P0[u], src);
                float inv = 1.0f / pr[kk];
                invs[kk] = inv;
                float f0 = (lane > k) ? P0[kk] * inv : 0.f;
                float f1 = ((lane + 64) > k) ? P1[kk] * inv : 0.f;
                #pragma unroll
                for (int u = kk + 1; u < 16; ++u) {
                    P0[u] -= f0 * pr[u];
                    P1[u] -= f1 * pr[u];
                }
            }
            #pragma unroll
            for (int u = 0; u < 16; ++u) {
                sm->chol.Cs[lane][k0 + u] = P0[u];
                sm->chol.Cs[lane + 64][k0 + u] = P1[u];
            }
            if (lane == 0) {
                #pragma unroll
                for (int kk = 0; kk < 16; ++kk) sm->chol.inv_d[kk] = invs[kk];
            }
        }
        __syncthreads();
        int base = k0 + 16;
        if (base < 128) {
            int h = tid >> 6, c = tid & 63;
            int j1 = base + c;
            int j2 = base + c + 64;
            bool has1 = (j1 < 128), has2 = (j2 < 128);
            float w1[16], w2[16];
            if (has1) {
                #pragma unroll
                for (int u = 0; u < 16; ++u) w1[u] = sm->chol.Cs[j1][k0 + u] * sm->chol.inv_d[u];
            }
            if (has2) {
                #pragma unroll
                for (int u = 0; u < 16; ++u) w2[u] = sm->chol.Cs[j2][k0 + u] * sm->chol.inv_d[u];
            }
            int rlo = h * 32;
            int istart = rlo > base ? rlo : base;
            for (int i = istart; i < rlo + 32; ++i) {
                float v[16];
                #pragma unroll
                for (int u = 0; u < 16; ++u) v[u] = sm->chol.Cs[i][k0 + u];
                float a1 = 0.f, a2 = 0.f;
                #pragma unroll
                for (int u = 0; u < 16; ++u) { a1 += v[u] * w1[u]; a2 += v[u] * w2[u]; }
                if (has1) sm->chol.Cs[i][j1] -= a1;
                if (has2) sm->chol.Cs[i][j2] -= a2;
            }
        }
        __syncthreads();
    }
    for (int f = tid; f < 128 * 128; f += 256) {
        int k = f >> 7, i = f & 127;
        float d = sm->chol.Cs[k][k];
        float irs = 1.0f / sqrtf(d);
        float v;
        if (i < k) v = 0.f;
        else if (i == k) v = irs;
        else v = sm->chol.Cs[i][k] * irs;
        Lt[f] = v;
    }
}

// Forward solve L*X = sum of ns RHS slabs. 32 cols/block; band h = 16 rows in regs.
__device__ __forceinline__ void dev_trsm(Smem* sm, const float* Lt, const float* RHS,
                                         int ns, float* Qt, int bid) {
    int tid = threadIdx.x;
    int c = tid & 31, h = tid >> 5;
    int j0 = bid * 32;
    {
        const float4* src = (const float4*)Lt;
        float4* dst = (float4*)sm->trsm.Ls;
        for (int f = tid; f < 4096; f += 256) dst[f] = src[f];
    }
    float acc[16];
    #pragma unroll
    for (int r = 0; r < 16; ++r) {
        int row = h * 16 + r;
        float s = RHS[row * 1024 + j0 + c];
        for (int z = 1; z < ns; ++z) s += RHS[z * 131072 + row * 1024 + j0 + c];
        acc[r] = s;
    }
    __syncthreads();
    float* Ls = sm->trsm.Ls;
    for (int pb = 0; pb < 8; ++pb) {
        int p0 = pb * 16;
        if (h == pb) {
            #pragma unroll
            for (int kk = 0; kk < 16; ++kk) {
                int k = p0 + kk;
                float x = acc[kk] * Ls[k * 128 + k];   // diag = 1/L
                acc[kk] = x;
                sm->trsm.Xs[kk][c] = x;
                #pragma unroll
                for (int r = kk + 1; r < 16; ++r)
                    acc[r] -= Ls[k * 128 + p0 + r] * x;
            }
        }
        __syncthreads();
        if (h > pb) {
            int rb = h * 16;
            #pragma unroll
            for (int kk = 0; kk < 16; ++kk) {
                float x = sm->trsm.Xs[kk][c];
                const float4* lr = (const float4*)&Ls[(p0 + kk) * 128 + rb];
                #pragma unroll
                for (int g4 = 0; g4 < 4; ++g4) {
                    float4 lv = lr[g4];
                    acc[g4 * 4 + 0] -= lv.x * x;
                    acc[g4 * 4 + 1] -= lv.y * x;
                    acc[g4 * 4 + 2] -= lv.z * x;
                    acc[g4 * 4 + 3] -= lv.w * x;
                }
            }
        }
        __syncthreads();
    }
    #pragma unroll
    for (int r = 0; r < 16; ++r)
        Qt[(h * 16 + r) * 1024 + j0 + c] = acc[r];
}

// G = 8*Qt^T Qt + per-block row abs-sum partials
__device__ __forceinline__ void dev_gemmG(Smem* sm, const float* Qt, float* G,
                                          float* Rpart, int bid) {
    int tid = threadIdx.x;
    int tx = tid & 15, ty = tid >> 4;
    int bx = bid & 15, by = bid >> 4;
    int a0 = by * 64, b0 = bx * 64;
    float acc[4][4] = {};
    for (int kc = 0; kc < 128; kc += 32) {
        for (int pass = 0; pass < 8; ++pass) {
            int idx = pass * 256 + tid;
            int r = idx >> 6, cc = idx & 63;
            sm->gg.As[r][cc] = Qt[(kc + r) * 1024 + a0 + cc];
            sm->gg.Bs[r][cc] = Qt[(kc + r) * 1024 + b0 + cc];
        }
        __syncthreads();
        for (int k = 0; k < 32; ++k) {
            float4 av = *(const float4*)&sm->gg.As[k][ty * 4];
            float4 bv = *(const float4*)&sm->gg.Bs[k][tx * 4];
            float a[4] = {av.x, av.y, av.z, av.w};
            float b[4] = {bv.x, bv.y, bv.z, bv.w};
            #pragma unroll
            for (int i = 0; i < 4; ++i)
                #pragma unroll
                for (int j = 0; j < 4; ++j) acc[i][j] += a[i] * b[j];
        }
        __syncthreads();
    }
    float rsum[4] = {0.f, 0.f, 0.f, 0.f};
    for (int i = 0; i < 4; ++i) {
        int aa = a0 + ty * 4 + i;
        float g[4];
        #pragma unroll
        for (int j = 0; j < 4; ++j) g[j] = 8.f * acc[i][j];
        *(float4*)&G[aa * 1024 + b0 + tx * 4] = make_float4(g[0], g[1], g[2], g[3]);
        int bb = b0 + tx * 4;
        #pragma unroll
        for (int j = 0; j < 4; ++j) rsum[i] += (aa == bb + j) ? 0.f : fabsf(g[j]);
    }
    for (int i = 0; i < 4; ++i) sm->gg.Rs[ty * 4 + i][tx] = rsum[i];
    __syncthreads();
    if (tid < 64) {
        float s = 0.f;
        for (int x = 0; x < 16; ++x) s += sm->gg.Rs[tid][x];
        Rpart[bx * 1024 + a0 + tid] = s;
    }
}

// Ri[1024] into sm->gy.Ri; returns rth/delta (all threads)
__device__ __forceinline__ void dev_ri(Smem* sm, const float* Rpart,
                                       float* rth, float* delta) {
    int tid = threadIdx.x;
    float mn = 3.4e38f;
    for (int i = tid; i < 1024; i += 256) {
        float s = 0.f;
        #pragma unroll
        for (int x = 0; x < 16; ++x) s += Rpart[x * 1024 + i];
        sm->gy.Ri[i] = s;
        mn = fminf(mn, s);
    }
    sm->gy.red[tid] = mn;
    __syncthreads();
    for (int w = 128; w > 0; w >>= 1) {
        if (tid < w) sm->gy.red[tid] = fminf(sm->gy.red[tid], sm->gy.red[tid + w]);
        __syncthreads();
    }
    float r = sm->gy.red[0];
    *rth = r;
    *delta = r / 1023.f;
}

// Yslab[kz] = Qt * G' over K-chunk kz (256 wide); mask fused; Ri from LDS.
__device__ __forceinline__ void dev_gemmY(Smem* sm, const float* Qt, const float* G,
                                          float rth, float delta, float* Yslab, int bid) {
    int tid = threadIdx.x;
    int j0 = (bid & 15) * 64;
    int m0 = ((bid >> 4) & 1) * 64;
    int kz = bid >> 5;
    int kc0 = kz * 256;
    int tx = tid & 15, ty = tid >> 4;
    float acc[4][4] = {};
    for (int kc = kc0; kc < kc0 + 256; kc += 32) {
        for (int i = tid; i < 2048; i += 256) {
            int k = i & 31, m = i >> 5;
            sm->gy.As[k][m] = Qt[(m0 + m) * 1024 + kc + k];
        }
        for (int i = tid; i < 2048; i += 256) {
            int n = i & 63, k = i >> 6;
            int a = kc + k, b = j0 + n;
            float g = G[a * 1024 + b];
            float sg = delta * ((g > 0.f) ? 1.f : ((g < 0.f) ? -1.f : 0.f));
            float ga = (sm->gy.Ri[a] > rth) ? sg : g;
            float gb = (sm->gy.Ri[b] > rth) ? sg : g;
            sm->gy.Bs[k][n] = (a == b) ? g : 0.5f * (ga + gb);
        }
        __syncthreads();
        for (int k = 0; k < 32; ++k) {
            float4 av = *(const float4*)&sm->gy.As[k][ty * 4];
            float4 bv = *(const float4*)&sm->gy.Bs[k][tx * 4];
            float a[4] = {av.x, av.y, av.z, av.w};
            float b[4] = {bv.x, bv.y, bv.z, bv.w};
            #pragma unroll
            for (int i = 0; i < 4; ++i)
                #pragma unroll
                for (int j = 0; j < 4; ++j) acc[i][j] += a[i] * b[j];
        }
        __syncthreads();
    }
    float* outp = &Yslab[kz * 131072];
    for (int i = 0; i < 4; ++i)
        *(float4*)&outp[(m0 + ty * 4 + i) * 1024 + j0 + tx * 4] =
            make_float4(acc[i][0], acc[i][1], acc[i][2], acc[i][3]);
}

// trB partial: S-tile = (Qt^T Qt)[64x64] in regs; s += sum G'(G_old)⊙S ; atomicAdd
__device__ __forceinline__ void dev_trB(Smem* sm, const float* Qt, const float* G,
                                        const float* Rpart, float* accb, int bid) {
    int tid = threadIdx.x;
    float rth, delta;
    dev_ri(sm, Rpart, &rth, &delta);
    __syncthreads();
    int tx = tid & 15, ty = tid >> 4;
    int a0 = (bid >> 4) * 64, b0 = (bid & 15) * 64;
    float acc[4][4] = {};
    for (int kc = 0; kc < 128; kc += 32) {
        for (int pass = 0; pass < 8; ++pass) {
            int idx = pass * 256 + tid;
            int r = idx >> 6, cc = idx & 63;
            sm->gy.As[r][cc] = Qt[(kc + r) * 1024 + a0 + cc];
            sm->gy.Bs[r][cc] = Qt[(kc + r) * 1024 + b0 + cc];
        }
        __syncthreads();
        for (int k = 0; k < 32; ++k) {
            float4 av = *(const float4*)&sm->gy.As[k][ty * 4];
            float4 bv = *(const float4*)&sm->gy.Bs[k][tx * 4];
            float a[4] = {av.x, av.y, av.z, av.w};
            float b[4] = {bv.x, bv.y, bv.z, bv.w};
            #pragma unroll
            for (int i = 0; i < 4; ++i)
                #pragma unroll
                for (int j = 0; j < 4; ++j) acc[i][j] += a[i] * b[j];
        }
        __syncthreads();
    }
    float s = 0.f;
    for (int i = 0; i < 4; ++i) {
        int aa = a0 + ty * 4 + i;
        float ria = sm->gy.Ri[aa];
        for (int j = 0; j < 4; ++j) {
            int bb = b0 + tx * 4 + j;
            float g = G[aa * 1024 + bb];
            float sg = delta * ((g > 0.f) ? 1.f : ((g < 0.f) ? -1.f : 0.f));
            float ga = (ria > rth) ? sg : g;
            float gb = (sm->gy.Ri[bb] > rth) ? sg : g;
            float gp = (aa == bb) ? g : 0.5f * (ga + gb);
            s += gp * acc[i][j];
        }
    }
    __syncthreads();
    sm->gy.red[tid] = s;
    __syncthreads();
    for (int w = 128; w > 0; w >>= 1) {
        if (tid < w) sm->gy.red[tid] += sm->gy.red[tid + w];
        __syncthreads();
    }
    if (tid == 0) atomicAdd(&accb[2], sm->gy.red[0]);
}

__global__ __launch_bounds__(256) void mega(const float* __restrict__ t1,
                                            const float* __restrict__ t2,
                                            const float* __restrict__ params,
                                            const float* __restrict__ tmin,
                                            const float* __restrict__ tmax,
                                            const float* __restrict__ beta,
                                            const float* __restrict__ R,
                                            float* ws, float* out) {
    float* G     = ws + OFF_G;
    float* Qt    = ws + OFF_QT;
    float* Yslab = ws + OFF_YS;
    float* Cslab = ws + OFF_CS;
    float* Lt    = ws + OFF_LT;
    float* Rpart = ws + OFF_RP;
    float* accb  = ws + OFF_ACC;
    unsigned* cnt = (unsigned*)(ws + OFF_BAR);
    unsigned* gen = cnt + 1;
    __shared__ Smem sm;
    int bid = blockIdx.x;

    // P0: syrk(R) on blocks 0..31; loss stats on the rest (accb pre-zeroed by memset)
    if (bid < 32) dev_syrk(&sm, R, 1, R, 1, Cslab, bid);
    else if (bid < 250) dev_match(&sm, t1, t2, accb, bid - 32);
    else if (bid == 250) dev_range(&sm, params, tmin, tmax, accb);
    else if (bid < 255) dev_sumsq(&sm, R, accb, bid - 251);
    gridbar(cnt, gen);
    // P1: chol
    if (bid == 0) dev_chol(&sm, Cslab, Lt);
    gridbar(cnt, gen);
    // P2: Q0 = L^-1 R
    if (bid < 32) dev_trsm(&sm, Lt, R, 1, Qt, bid);
    gridbar(cnt, gen);

    for (int it = 0; it < 50; ++it) {
        dev_gemmG(&sm, Qt, G, Rpart, bid);
        gridbar(cnt, gen);
        if (bid < 128) {
            float rth, delta;
            dev_ri(&sm, Rpart, &rth, &delta);
            dev_gemmY(&sm, Qt, G, rth, delta, Yslab, bid);
        }
        gridbar(cnt, gen);
        if (bid < 32) dev_syrk(&sm, Yslab, 4, Yslab, 4, Cslab, bid);
        gridbar(cnt, gen);
        if (bid == 0) dev_chol(&sm, Cslab, Lt);
        gridbar(cnt, gen);
        if (bid < 32) dev_trsm(&sm, Lt, Yslab, 4, Qt, bid);
        gridbar(cnt, gen);
    }

    // epilogue: trB = sum G'(G_49) ⊙ (Q50^T Q50), using Rpart_49 still in ws
    dev_trB(&sm, Qt, G, Rpart, accb, bid);
    gridbar(cnt, gen);
    if (bid == 0 && threadIdx.x == 0)
        out[0] = accb[0] / 4194304.f + beta[0] * (accb[1] / 2176.f)
               + (accb[2] + accb[3]) / 131072.f;
}

extern "C" void kernel_launch(void* const* d_in, const int* in_sizes, int n_in,
                              void* d_out, int out_size, void* d_ws, size_t ws_size,
                              hipStream_t stream) {
    const float* t1 = (const float*)d_in[0];
    const float* t2 = (const float*)d_in[1];
    const float* params = (const float*)d_in[2];
    const float* tmin = (const float*)d_in[3];
    const float* tmax = (const float*)d_in[4];
    const float* beta = (const float*)d_in[5];
    const float* R = (const float*)d_in[6];
    float* ws = (float*)d_ws;
    float* out = (float*)d_out;

    // zero accumulators (4 floats) + barrier state (2 uints) in one memset
    hipMemsetAsync(ws + OFF_ACC, 0, 24, stream);
    mega<<<NBLK, 256, 0, stream>>>(t1, t2, params, tmin, tmax, beta, R, ws, out);
}

// Round 5
// 13595.078 us; speedup vs baseline: 1.2628x; 1.2628x over previous
//
#include <hip/hip_runtime.h>

#define NBLK 256

// workspace layout (floats)
#define OFF_G    0            // 1024*1024
#define OFF_QT   1048576      // 128*1024
#define OFF_YS   1179648      // 4 slabs * 128*1024
#define OFF_CS   1703936      // 8 slabs * 128*128
#define OFF_LT   1835008      // 128*128
#define OFF_RP   1851392      // 16*1024
#define OFF_ACC  1867776      // 4 floats: match, range, trB, normR
#define OFF_BAR  1867792      // 64 counters (stride 16 u32) + gen  (64B-aligned)

union Smem {
    struct { float As[128][68]; float Bs[128][68]; } syrk;        // 69632 B
    struct { float Cs[128][129]; float inv_d[16]; } chol;         // 66112 B
    struct { float Ls[128 * 128]; float Xs[16][32]; } trsm;       // 67584 B
    struct { float As[32][68]; float Bs[32][68]; float Rs[64][16]; } gg;
    struct { float Ri[1024]; float red[256]; float As[32][33]; float Bs[32][68]; } gy;
    struct { float Ri[1024]; float red[256]; float As[32][68]; float Bs[32][68]; } tb;
    float red[256];
};

// Distributed-counter grid barrier: arrivals spread over 64 counters (64B apart,
// monotonic); block 0 wave-0 polls all 64 in parallel, then releases `gen`.
__device__ __forceinline__ void gridbar(unsigned* cnt, unsigned* gen, unsigned ph) {
    __syncthreads();
    int tid = threadIdx.x;
    if (blockIdx.x == 0) {
        if (tid == 0)
            __hip_atomic_fetch_add(&cnt[0], 1u, __ATOMIC_RELEASE, __HIP_MEMORY_SCOPE_AGENT);
        if (tid < 64) {
            unsigned target = ph * (NBLK / 64);
            while (__hip_atomic_load(&cnt[tid * 16], __ATOMIC_ACQUIRE,
                                     __HIP_MEMORY_SCOPE_AGENT) < target)
                __builtin_amdgcn_s_sleep(1);
        }
        if (tid == 0)
            __hip_atomic_store(gen, ph, __ATOMIC_RELEASE, __HIP_MEMORY_SCOPE_AGENT);
    } else {
        if (tid == 0) {
            __hip_atomic_fetch_add(&cnt[(blockIdx.x & 63) * 16], 1u,
                                   __ATOMIC_RELEASE, __HIP_MEMORY_SCOPE_AGENT);
            while (__hip_atomic_load(gen, __ATOMIC_RELAXED,
                                     __HIP_MEMORY_SCOPE_AGENT) < ph)
                __builtin_amdgcn_s_sleep(1);
            (void)__hip_atomic_load(gen, __ATOMIC_ACQUIRE, __HIP_MEMORY_SCOPE_AGENT);
        }
    }
    __syncthreads();
}

__device__ __forceinline__ void dev_match(Smem* sm, const float* t1, const float* t2,
                                          float* accb, int w) {
    int tid = threadIdx.x;
    const float4* a = (const float4*)t1;
    const float4* b = (const float4*)t2;
    float s = 0.f;
    for (int i = w * 256 + tid; i < 1048576; i += 218 * 256) {
        float4 x = a[i], y = b[i];
        float d0 = x.x - y.x, d1 = x.y - y.y, d2 = x.z - y.z, d3 = x.w - y.w;
        s += d0 * d0 + d1 * d1 + d2 * d2 + d3 * d3;
    }
    sm->red[tid] = s; __syncthreads();
    for (int w2 = 128; w2 > 0; w2 >>= 1) {
        if (tid < w2) sm->red[tid] += sm->red[tid + w2];
        __syncthreads();
    }
    if (tid == 0) atomicAdd(&accb[0], sm->red[0]);
}

__device__ __forceinline__ void dev_range(Smem* sm, const float* params, const float* tmin,
                                          const float* tmax, float* accb) {
    int tid = threadIdx.x;
    float a = tmin[0], b = tmax[0];
    const float d = 0.01f;
    float s = 0.f;
    for (int i = tid; i < 128 * 17; i += 256) {
        float p = params[i];
        float r1 = (p - a - d) / (-d);
        float r2 = (p - b + d) / d;
        s += fmaxf(fmaxf(r1, r2), 0.f);
    }
    sm->red[tid] = s; __syncthreads();
    for (int w = 128; w > 0; w >>= 1) {
        if (tid < w) sm->red[tid] += sm->red[tid + w];
        __syncthreads();
    }
    if (tid == 0) atomicAdd(&accb[1], sm->red[0]);
}

__device__ __forceinline__ void dev_sumsq(Smem* sm, const float* X, float* accb, int w) {
    int tid = threadIdx.x;
    float s = 0.f;
    for (int i = w * 256 + tid; i < 131072; i += 1024) { float v = X[i]; s += v * v; }
    sm->red[tid] = s; __syncthreads();
    for (int w2 = 128; w2 > 0; w2 >>= 1) {
        if (tid < w2) sm->red[tid] += sm->red[tid + w2];
        __syncthreads();
    }
    if (tid == 0) atomicAdd(&accb[3], sm->red[0]);
}

// Cslab[z] = A_eff(64 rows p0) x B_eff(64 rows q0) over K-chunk z of 128
__device__ __forceinline__ void dev_syrk(Smem* sm, const float* A, int nsA,
                                         const float* B, int nsB, float* Cslab, int bid) {
    int tid = threadIdx.x;
    int q0 = (bid & 1) * 64, p0 = ((bid >> 1) & 1) * 64, z = bid >> 2;
    int kc = z * 128;
    for (int i = tid; i < 8192; i += 256) {
        int r = i >> 7, c = i & 127;
        float s = 0.f;
        for (int zz = 0; zz < nsA; ++zz) s += A[zz * 131072 + (p0 + r) * 1024 + kc + c];
        sm->syrk.As[c][r] = s;
    }
    for (int i = tid; i < 8192; i += 256) {
        int r = i >> 7, c = i & 127;
        float s = 0.f;
        for (int zz = 0; zz < nsB; ++zz) s += B[zz * 131072 + (q0 + r) * 1024 + kc + c];
        sm->syrk.Bs[c][r] = s;
    }
    __syncthreads();
    int tx = tid & 15, ty = tid >> 4;
    float acc[4][4] = {};
    for (int k = 0; k < 128; ++k) {
        float4 av = *(const float4*)&sm->syrk.As[k][ty * 4];
        float4 bv = *(const float4*)&sm->syrk.Bs[k][tx * 4];
        float a[4] = {av.x, av.y, av.z, av.w};
        float b[4] = {bv.x, bv.y, bv.z, bv.w};
        #pragma unroll
        for (int i = 0; i < 4; ++i)
            #pragma unroll
            for (int j = 0; j < 4; ++j) acc[i][j] += a[i] * b[j];
    }
    float* outp = &Cslab[z * 16384];
    for (int i = 0; i < 4; ++i)
        *(float4*)&outp[(p0 + ty * 4 + i) * 128 + q0 + tx * 4] =
            make_float4(acc[i][0], acc[i][1], acc[i][2], acc[i][3]);
}

// Blocked Cholesky; panel in one wave's registers (shfl), rank-16 trailing update.
// Lt[k*128+i] = L[i][k] for i>k; diag holds 1/L[k][k]; 0 above.
__device__ __forceinline__ void dev_chol(Smem* sm, const float* Cslab, float* Lt) {
    int tid = threadIdx.x;
    const float4* C4 = (const float4*)Cslab;
    for (int f4 = tid; f4 < 4096; f4 += 256) {
        float4 s = C4[f4];
        #pragma unroll
        for (int z = 1; z < 8; ++z) {
            float4 v = C4[z * 4096 + f4];
            s.x += v.x; s.y += v.y; s.z += v.z; s.w += v.w;
        }
        int f = f4 << 2;
        int r = f >> 7, c = f & 127;
        sm->chol.Cs[r][c] = s.x;
        sm->chol.Cs[r][c + 1] = s.y;
        sm->chol.Cs[r][c + 2] = s.z;
        sm->chol.Cs[r][c + 3] = s.w;
    }
    __syncthreads();
    int lane = tid & 63;
    for (int kb = 0; kb < 8; ++kb) {
        int k0 = kb * 16;
        if (tid < 64) {
            float P0[16], P1[16], invs[16];
            #pragma unroll
            for (int u = 0; u < 16; ++u) {
                P0[u] = sm->chol.Cs[lane][k0 + u];
                P1[u] = sm->chol.Cs[lane + 64][k0 + u];
            }
            #pragma unroll
            for (int kk = 0; kk < 16; ++kk) {
                int k = k0 + kk;
                int src = k & 63;
                bool hi = (k >= 64);
                float pr[16];
                #pragma unroll
                for (int u = 0; u < 16; ++u)
                    if (u >= kk) pr[u] = __shfl(hi ? P1[u] : P0[u], src);
                float inv = 1.0f / pr[kk];
                invs[kk] = inv;
                float f0 = (lane > k) ? P0[kk] * inv : 0.f;
                float f1 = ((lane + 64) > k) ? P1[kk] * inv : 0.f;
                #pragma unroll
                for (int u = kk + 1; u < 16; ++u) {
                    P0[u] -= f0 * pr[u];
                    P1[u] -= f1 * pr[u];
                }
            }
            #pragma unroll
            for (int u = 0; u < 16; ++u) {
                sm->chol.Cs[lane][k0 + u] = P0[u];
                sm->chol.Cs[lane + 64][k0 + u] = P1[u];
            }
            if (lane == 0) {
                #pragma unroll
                for (int kk = 0; kk < 16; ++kk) sm->chol.inv_d[kk] = invs[kk];
            }
        }
        __syncthreads();
        int base = k0 + 16;
        if (base < 128) {
            int h = tid >> 6, c = tid & 63;
            int j1 = base + c;
            int j2 = base + c + 64;
            bool has1 = (j1 < 128), has2 = (j2 < 128);
            float w1[16], w2[16];
            if (has1) {
                #pragma unroll
                for (int u = 0; u < 16; ++u) w1[u] = sm->chol.Cs[j1][k0 + u] * sm->chol.inv_d[u];
            }
            if (has2) {
                #pragma unroll
                for (int u = 0; u < 16; ++u) w2[u] = sm->chol.Cs[j2][k0 + u] * sm->chol.inv_d[u];
            }
            int rlo = h * 32;
            int istart = rlo > base ? rlo : base;
            for (int i = istart; i < rlo + 32; ++i) {
                float v[16];
                #pragma unroll
                for (int u = 0; u < 16; ++u) v[u] = sm->chol.Cs[i][k0 + u];
                float a1 = 0.f, a2 = 0.f;
                #pragma unroll
                for (int u = 0; u < 16; ++u) { a1 += v[u] * w1[u]; a2 += v[u] * w2[u]; }
                if (has1) sm->chol.Cs[i][j1] -= a1;
                if (has2) sm->chol.Cs[i][j2] -= a2;
            }
        }
        __syncthreads();
    }
    for (int f = tid; f < 128 * 128; f += 256) {
        int k = f >> 7, i = f & 127;
        float d = sm->chol.Cs[k][k];
        float irs = 1.0f / sqrtf(d);
        float v;
        if (i < k) v = 0.f;
        else if (i == k) v = irs;
        else v = sm->chol.Cs[i][k] * irs;
        Lt[f] = v;
    }
}

// Forward solve L*X = sum of ns RHS slabs. 32 cols/block; band h = 16 rows in regs.
__device__ __forceinline__ void dev_trsm(Smem* sm, const float* Lt, const float* RHS,
                                         int ns, float* Qt, int bid) {
    int tid = threadIdx.x;
    int c = tid & 31, h = tid >> 5;
    int j0 = bid * 32;
    {
        const float4* src = (const float4*)Lt;
        float4* dst = (float4*)sm->trsm.Ls;
        for (int f = tid; f < 4096; f += 256) dst[f] = src[f];
    }
    float acc[16];
    #pragma unroll
    for (int r = 0; r < 16; ++r) {
        int row = h * 16 + r;
        float s = RHS[row * 1024 + j0 + c];
        for (int z = 1; z < ns; ++z) s += RHS[z * 131072 + row * 1024 + j0 + c];
        acc[r] = s;
    }
    __syncthreads();
    float* Ls = sm->trsm.Ls;
    for (int pb = 0; pb < 8; ++pb) {
        int p0 = pb * 16;
        if (h == pb) {
            #pragma unroll
            for (int kk = 0; kk < 16; ++kk) {
                int k = p0 + kk;
                float x = acc[kk] * Ls[k * 128 + k];   // diag = 1/L
                acc[kk] = x;
                sm->trsm.Xs[kk][c] = x;
                #pragma unroll
                for (int r = kk + 1; r < 16; ++r)
                    acc[r] -= Ls[k * 128 + p0 + r] * x;
            }
        }
        __syncthreads();
        if (h > pb) {
            int rb = h * 16;
            #pragma unroll
            for (int kk = 0; kk < 16; ++kk) {
                float x = sm->trsm.Xs[kk][c];
                const float4* lr = (const float4*)&Ls[(p0 + kk) * 128 + rb];
                #pragma unroll
                for (int g4 = 0; g4 < 4; ++g4) {
                    float4 lv = lr[g4];
                    acc[g4 * 4 + 0] -= lv.x * x;
                    acc[g4 * 4 + 1] -= lv.y * x;
                    acc[g4 * 4 + 2] -= lv.z * x;
                    acc[g4 * 4 + 3] -= lv.w * x;
                }
            }
        }
        __syncthreads();
    }
    #pragma unroll
    for (int r = 0; r < 16; ++r)
        Qt[(h * 16 + r) * 1024 + j0 + c] = acc[r];
}

// G = 8*Qt^T Qt + per-block row abs-sum partials
__device__ __forceinline__ void dev_gemmG(Smem* sm, const float* Qt, float* G,
                                          float* Rpart, int bid) {
    int tid = threadIdx.x;
    int tx = tid & 15, ty = tid >> 4;
    int bx = bid & 15, by = bid >> 4;
    int a0 = by * 64, b0 = bx * 64;
    float acc[4][4] = {};
    for (int kc = 0; kc < 128; kc += 32) {
        for (int pass = 0; pass < 8; ++pass) {
            int idx = pass * 256 + tid;
            int r = idx >> 6, cc = idx & 63;
            sm->gg.As[r][cc] = Qt[(kc + r) * 1024 + a0 + cc];
            sm->gg.Bs[r][cc] = Qt[(kc + r) * 1024 + b0 + cc];
        }
        __syncthreads();
        for (int k = 0; k < 32; ++k) {
            float4 av = *(const float4*)&sm->gg.As[k][ty * 4];
            float4 bv = *(const float4*)&sm->gg.Bs[k][tx * 4];
            float a[4] = {av.x, av.y, av.z, av.w};
            float b[4] = {bv.x, bv.y, bv.z, bv.w};
            #pragma unroll
            for (int i = 0; i < 4; ++i)
                #pragma unroll
                for (int j = 0; j < 4; ++j) acc[i][j] += a[i] * b[j];
        }
        __syncthreads();
    }
    float rsum[4] = {0.f, 0.f, 0.f, 0.f};
    for (int i = 0; i < 4; ++i) {
        int aa = a0 + ty * 4 + i;
        float g[4];
        #pragma unroll
        for (int j = 0; j < 4; ++j) g[j] = 8.f * acc[i][j];
        *(float4*)&G[aa * 1024 + b0 + tx * 4] = make_float4(g[0], g[1], g[2], g[3]);
        int bb = b0 + tx * 4;
        #pragma unroll
        for (int j = 0; j < 4; ++j) rsum[i] += (aa == bb + j) ? 0.f : fabsf(g[j]);
    }
    for (int i = 0; i < 4; ++i) sm->gg.Rs[ty * 4 + i][tx] = rsum[i];
    __syncthreads();
    if (tid < 64) {
        float s = 0.f;
        for (int x = 0; x < 16; ++x) s += sm->gg.Rs[tid][x];
        Rpart[bx * 1024 + a0 + tid] = s;
    }
}

// Ri[1024] into sm Ri; returns rth/delta (all threads)
__device__ __forceinline__ void dev_ri(Smem* sm, const float* Rpart,
                                       float* rth, float* delta) {
    int tid = threadIdx.x;
    float mn = 3.4e38f;
    for (int i = tid; i < 1024; i += 256) {
        float s = 0.f;
        #pragma unroll
        for (int x = 0; x < 16; ++x) s += Rpart[x * 1024 + i];
        sm->gy.Ri[i] = s;
        mn = fminf(mn, s);
    }
    sm->gy.red[tid] = mn;
    __syncthreads();
    for (int w = 128; w > 0; w >>= 1) {
        if (tid < w) sm->gy.red[tid] = fminf(sm->gy.red[tid], sm->gy.red[tid + w]);
        __syncthreads();
    }
    float r = sm->gy.red[0];
    *rth = r;
    *delta = r / 1023.f;
}

// Yslab[kz] = Qt * G' over K-chunk kz (256 wide); mask fused; Ri from LDS.
// 256 blocks: 16 (j) x 4 (m, 32-row tiles) x 4 (kz). acc 2x4 per thread.
__device__ __forceinline__ void dev_gemmY(Smem* sm, const float* Qt, const float* G,
                                          float rth, float delta, float* Yslab, int bid) {
    int tid = threadIdx.x;
    int j0 = (bid & 15) * 64;
    int m0 = ((bid >> 4) & 3) * 32;
    int kz = bid >> 6;
    int kc0 = kz * 256;
    int tx = tid & 15, ty = tid >> 4;
    float acc[2][4] = {};
    for (int kc = kc0; kc < kc0 + 256; kc += 32) {
        for (int i = tid; i < 1024; i += 256) {
            int k = i & 31, m = i >> 5;
            sm->gy.As[k][m] = Qt[(m0 + m) * 1024 + kc + k];
        }
        for (int i = tid; i < 2048; i += 256) {
            int n = i & 63, k = i >> 6;
            int a = kc + k, b = j0 + n;
            float g = G[a * 1024 + b];
            float sg = delta * ((g > 0.f) ? 1.f : ((g < 0.f) ? -1.f : 0.f));
            float ga = (sm->gy.Ri[a] > rth) ? sg : g;
            float gb = (sm->gy.Ri[b] > rth) ? sg : g;
            sm->gy.Bs[k][n] = (a == b) ? g : 0.5f * (ga + gb);
        }
        __syncthreads();
        for (int k = 0; k < 32; ++k) {
            float a0v = sm->gy.As[k][ty * 2], a1v = sm->gy.As[k][ty * 2 + 1];
            float4 bv = *(const float4*)&sm->gy.Bs[k][tx * 4];
            acc[0][0] += a0v * bv.x; acc[0][1] += a0v * bv.y;
            acc[0][2] += a0v * bv.z; acc[0][3] += a0v * bv.w;
            acc[1][0] += a1v * bv.x; acc[1][1] += a1v * bv.y;
            acc[1][2] += a1v * bv.z; acc[1][3] += a1v * bv.w;
        }
        __syncthreads();
    }
    float* outp = &Yslab[kz * 131072];
    for (int i = 0; i < 2; ++i)
        *(float4*)&outp[(m0 + ty * 2 + i) * 1024 + j0 + tx * 4] =
            make_float4(acc[i][0], acc[i][1], acc[i][2], acc[i][3]);
}

// trB partial: S-tile = (Qt^T Qt)[64x64] in regs; s += sum G'(G_old)⊙S ; atomicAdd
__device__ __forceinline__ void dev_trB(Smem* sm, const float* Qt, const float* G,
                                        const float* Rpart, float* accb, int bid) {
    int tid = threadIdx.x;
    float rth, delta;
    dev_ri(sm, Rpart, &rth, &delta);
    __syncthreads();
    int tx = tid & 15, ty = tid >> 4;
    int a0 = (bid >> 4) * 64, b0 = (bid & 15) * 64;
    float acc[4][4] = {};
    for (int kc = 0; kc < 128; kc += 32) {
        for (int pass = 0; pass < 8; ++pass) {
            int idx = pass * 256 + tid;
            int r = idx >> 6, cc = idx & 63;
            sm->tb.As[r][cc] = Qt[(kc + r) * 1024 + a0 + cc];
            sm->tb.Bs[r][cc] = Qt[(kc + r) * 1024 + b0 + cc];
        }
        __syncthreads();
        for (int k = 0; k < 32; ++k) {
            float4 av = *(const float4*)&sm->tb.As[k][ty * 4];
            float4 bv = *(const float4*)&sm->tb.Bs[k][tx * 4];
            float a[4] = {av.x, av.y, av.z, av.w};
            float b[4] = {bv.x, bv.y, bv.z, bv.w};
            #pragma unroll
            for (int i = 0; i < 4; ++i)
                #pragma unroll
                for (int j = 0; j < 4; ++j) acc[i][j] += a[i] * b[j];
        }
        __syncthreads();
    }
    float s = 0.f;
    for (int i = 0; i < 4; ++i) {
        int aa = a0 + ty * 4 + i;
        float ria = sm->tb.Ri[aa];
        for (int j = 0; j < 4; ++j) {
            int bb = b0 + tx * 4 + j;
            float g = G[aa * 1024 + bb];
            float sg = delta * ((g > 0.f) ? 1.f : ((g < 0.f) ? -1.f : 0.f));
            float ga = (ria > rth) ? sg : g;
            float gb = (sm->tb.Ri[bb] > rth) ? sg : g;
            float gp = (aa == bb) ? g : 0.5f * (ga + gb);
            s += gp * acc[i][j];
        }
    }
    __syncthreads();
    sm->tb.red[tid] = s;
    __syncthreads();
    for (int w = 128; w > 0; w >>= 1) {
        if (tid < w) sm->tb.red[tid] += sm->tb.red[tid + w];
        __syncthreads();
    }
    if (tid == 0) atomicAdd(&accb[2], sm->tb.red[0]);
}

__global__ __launch_bounds__(256) void mega(const float* __restrict__ t1,
                                            const float* __restrict__ t2,
                                            const float* __restrict__ params,
                                            const float* __restrict__ tmin,
                                            const float* __restrict__ tmax,
                                            const float* __restrict__ beta,
                                            const float* __restrict__ R,
                                            float* ws, float* out) {
    float* G     = ws + OFF_G;
    float* Qt    = ws + OFF_QT;
    float* Yslab = ws + OFF_YS;
    float* Cslab = ws + OFF_CS;
    float* Lt    = ws + OFF_LT;
    float* Rpart = ws + OFF_RP;
    float* accb  = ws + OFF_ACC;
    unsigned* cnt = (unsigned*)(ws + OFF_BAR);
    unsigned* gen = cnt + 64 * 16;
    __shared__ Smem sm;
    int bid = blockIdx.x;
    unsigned ph = 0;

    // P0: syrk(R) on blocks 0..31; loss stats on the rest (accb pre-zeroed by memset)
    if (bid < 32) dev_syrk(&sm, R, 1, R, 1, Cslab, bid);
    else if (bid < 250) dev_match(&sm, t1, t2, accb, bid - 32);
    else if (bid == 250) dev_range(&sm, params, tmin, tmax, accb);
    else if (bid < 255) dev_sumsq(&sm, R, accb, bid - 251);
    gridbar(cnt, gen, ++ph);
    // P1: chol
    if (bid == 0) dev_chol(&sm, Cslab, Lt);
    gridbar(cnt, gen, ++ph);
    // P2: Q0 = L^-1 R
    if (bid < 32) dev_trsm(&sm, Lt, R, 1, Qt, bid);
    gridbar(cnt, gen, ++ph);

    for (int it = 0; it < 50; ++it) {
        dev_gemmG(&sm, Qt, G, Rpart, bid);
        gridbar(cnt, gen, ++ph);
        {
            float rth, delta;
            dev_ri(&sm, Rpart, &rth, &delta);
            dev_gemmY(&sm, Qt, G, rth, delta, Yslab, bid);
        }
        gridbar(cnt, gen, ++ph);
        if (bid < 32) dev_syrk(&sm, Yslab, 4, Yslab, 4, Cslab, bid);
        gridbar(cnt, gen, ++ph);
        if (bid == 0) dev_chol(&sm, Cslab, Lt);
        gridbar(cnt, gen, ++ph);
        if (bid < 32) dev_trsm(&sm, Lt, Yslab, 4, Qt, bid);
        gridbar(cnt, gen, ++ph);
    }

    // epilogue: trB = sum G'(G_49) ⊙ (Q50^T Q50), using Rpart_49 still in ws
    dev_trB(&sm, Qt, G, Rpart, accb, bid);
    gridbar(cnt, gen, ++ph);
    if (bid == 0 && threadIdx.x == 0)
        out[0] = accb[0] / 4194304.f + beta[0] * (accb[1] / 2176.f)
               + (accb[2] + accb[3]) / 131072.f;
}

extern "C" void kernel_launch(void* const* d_in, const int* in_sizes, int n_in,
                              void* d_out, int out_size, void* d_ws, size_t ws_size,
                              hipStream_t stream) {
    const float* t1 = (const float*)d_in[0];
    const float* t2 = (const float*)d_in[1];
    const float* params = (const float*)d_in[2];
    const float* tmin = (const float*)d_in[3];
    const float* tmax = (const float*)d_in[4];
    const float* beta = (const float*)d_in[5];
    const float* R = (const float*)d_in[6];
    float* ws = (float*)d_ws;
    float* out = (float*)d_out;

    // zero accumulators + barrier counters/gen
    hipMemsetAsync(ws + OFF_ACC, 0, 4224, stream);
    mega<<<NBLK, 256, 0, stream>>>(t1, t2, params, tmin, tmax, beta, R, ws, out);
}

// Round 6
// 11202.109 us; speedup vs baseline: 1.5326x; 1.2136x over previous
//
#include <hip/hip_runtime.h>

#define NBLK 256

// workspace layout (floats)
#define OFF_G    0            // 1024*1024
#define OFF_QT   1048576      // 128*1024
#define OFF_YS   1179648      // 4 slabs * 128*1024
#define OFF_CS   1703936      // 8 slabs * 128*128
#define OFF_LT   1835008      // 128*128
#define OFF_RP   1851392      // 16*1024
#define OFF_ACC  1867776      // 4 floats: match, range, trB, normR
#define OFF_BAR  1867792      // 81 counter lines (stride 16 u32 = 64B)

// barrier counter line indices
#define BAR_A 0    // 32 lines, full barrier (256 arrive)
#define BAR_B 32   // 32 lines, 256 arrive / 32 wait
#define BAR_C 64   // 8 lines, 32 arrive / 1 wait
#define BAR_D 72   // 1 line, 1 arrive / 32 wait
#define BAR_E 73   // 8 lines, 32 arrive / 256 wait

typedef float v2f __attribute__((ext_vector_type(2)));

// ---- coherent (L1/L2-bypassing, fence-free) access helpers ----
__device__ __forceinline__ v2f ald2(const float* p) {
    unsigned long long u = __hip_atomic_load((const unsigned long long*)p,
                                             __ATOMIC_RELAXED, __HIP_MEMORY_SCOPE_AGENT);
    union { unsigned long long u; v2f f; } c; c.u = u; return c.f;
}
__device__ __forceinline__ void ast2(float* p, float a, float b) {
    union { unsigned long long u; float f[2]; } c; c.f[0] = a; c.f[1] = b;
    __hip_atomic_store((unsigned long long*)p, c.u,
                       __ATOMIC_RELAXED, __HIP_MEMORY_SCOPE_AGENT);
}
__device__ __forceinline__ float ald(const float* p) {
    return __hip_atomic_load(p, __ATOMIC_RELAXED, __HIP_MEMORY_SCOPE_AGENT);
}
__device__ __forceinline__ void ast(float* p, float x) {
    __hip_atomic_store(p, x, __ATOMIC_RELAXED, __HIP_MEMORY_SCOPE_AGENT);
}

// arrive: __syncthreads drains vmcnt(0) per wave (stores acked at coherence
// point), then one relaxed fetch_add. No fences, no L2 walks.
__device__ __forceinline__ void bar_arrive(unsigned* bb, int line) {
    __syncthreads();
    if (threadIdx.x == 0)
        __hip_atomic_fetch_add(bb + line * 16, 1u,
                               __ATOMIC_RELAXED, __HIP_MEMORY_SCOPE_AGENT);
}
__device__ __forceinline__ void bar_wait(unsigned* bb, int wbase, int nlines,
                                         unsigned tgt) {
    if ((int)threadIdx.x < nlines) {
        while (__hip_atomic_load(bb + (wbase + threadIdx.x) * 16,
                                 __ATOMIC_RELAXED, __HIP_MEMORY_SCOPE_AGENT) < tgt)
            __builtin_amdgcn_s_sleep(2);
    }
    __builtin_amdgcn_s_waitcnt(0);  // drain poll loads
    __syncthreads();
}

union Smem {
    struct { float As[128][68]; float Bs[128][68]; } syrk;        // 69632 B
    struct { float Cs[128][129]; float inv_d[16]; } chol;         // 66112 B
    struct { float Ls[128 * 128]; float Xs[16][32]; } trsm;       // 67584 B
    struct { float As[32][68]; float Bs[32][68]; float Rs[64][16]; } gg;
    struct { float Ri[1024]; float red[256]; float As[32][33]; float Bs[32][68]; } gy;
    float red[256];
};

__device__ __forceinline__ void dev_match(Smem* sm, const float* t1, const float* t2,
                                          float* accb, int w) {
    int tid = threadIdx.x;
    const float4* a = (const float4*)t1;
    const float4* b = (const float4*)t2;
    float s = 0.f;
    for (int i = w * 256 + tid; i < 1048576; i += 218 * 256) {
        float4 x = a[i], y = b[i];
        float d0 = x.x - y.x, d1 = x.y - y.y, d2 = x.z - y.z, d3 = x.w - y.w;
        s += d0 * d0 + d1 * d1 + d2 * d2 + d3 * d3;
    }
    sm->red[tid] = s; __syncthreads();
    for (int w2 = 128; w2 > 0; w2 >>= 1) {
        if (tid < w2) sm->red[tid] += sm->red[tid + w2];
        __syncthreads();
    }
    if (tid == 0) atomicAdd(&accb[0], sm->red[0]);
    __syncthreads();
}

__device__ __forceinline__ void dev_range(Smem* sm, const float* params, const float* tmin,
                                          const float* tmax, float* accb) {
    int tid = threadIdx.x;
    float a = tmin[0], b = tmax[0];
    const float d = 0.01f;
    float s = 0.f;
    for (int i = tid; i < 128 * 17; i += 256) {
        float p = params[i];
        float r1 = (p - a - d) / (-d);
        float r2 = (p - b + d) / d;
        s += fmaxf(fmaxf(r1, r2), 0.f);
    }
    sm->red[tid] = s; __syncthreads();
    for (int w = 128; w > 0; w >>= 1) {
        if (tid < w) sm->red[tid] += sm->red[tid + w];
        __syncthreads();
    }
    if (tid == 0) atomicAdd(&accb[1], sm->red[0]);
    __syncthreads();
}

__device__ __forceinline__ void dev_sumsq(Smem* sm, const float* X, float* accb, int w) {
    int tid = threadIdx.x;
    float s = 0.f;
    for (int i = w * 256 + tid; i < 131072; i += 1024) { float v = X[i]; s += v * v; }
    sm->red[tid] = s; __syncthreads();
    for (int w2 = 128; w2 > 0; w2 >>= 1) {
        if (tid < w2) sm->red[tid] += sm->red[tid + w2];
        __syncthreads();
    }
    if (tid == 0) atomicAdd(&accb[3], sm->red[0]);
    __syncthreads();
}

// Cslab[z] = A_eff(64 rows p0) x B_eff(64 rows q0) over K-chunk z of 128
__device__ __forceinline__ void dev_syrk(Smem* sm, const float* A, int nsA,
                                         const float* B, int nsB, float* Cslab, int bid) {
    int tid = threadIdx.x;
    int q0 = (bid & 1) * 64, p0 = ((bid >> 1) & 1) * 64, z = bid >> 2;
    int kc = z * 128;
    for (int i = tid; i < 4096; i += 256) {
        int r = i >> 6, c2 = (i & 63) << 1;
        v2f s = {0.f, 0.f};
        for (int zz = 0; zz < nsA; ++zz) {
            v2f v = ald2(&A[zz * 131072 + (p0 + r) * 1024 + kc + c2]);
            s.x += v.x; s.y += v.y;
        }
        sm->syrk.As[c2][r] = s.x; sm->syrk.As[c2 + 1][r] = s.y;
    }
    for (int i = tid; i < 4096; i += 256) {
        int r = i >> 6, c2 = (i & 63) << 1;
        v2f s = {0.f, 0.f};
        for (int zz = 0; zz < nsB; ++zz) {
            v2f v = ald2(&B[zz * 131072 + (q0 + r) * 1024 + kc + c2]);
            s.x += v.x; s.y += v.y;
        }
        sm->syrk.Bs[c2][r] = s.x; sm->syrk.Bs[c2 + 1][r] = s.y;
    }
    __syncthreads();
    int tx = tid & 15, ty = tid >> 4;
    float acc[4][4] = {};
    for (int k = 0; k < 128; ++k) {
        float4 av = *(const float4*)&sm->syrk.As[k][ty * 4];
        float4 bv = *(const float4*)&sm->syrk.Bs[k][tx * 4];
        float a[4] = {av.x, av.y, av.z, av.w};
        float b[4] = {bv.x, bv.y, bv.z, bv.w};
        #pragma unroll
        for (int i = 0; i < 4; ++i)
            #pragma unroll
            for (int j = 0; j < 4; ++j) acc[i][j] += a[i] * b[j];
    }
    float* outp = &Cslab[z * 16384];
    for (int i = 0; i < 4; ++i) {
        float* op = &outp[(p0 + ty * 4 + i) * 128 + q0 + tx * 4];
        ast2(op, acc[i][0], acc[i][1]);
        ast2(op + 2, acc[i][2], acc[i][3]);
    }
    __syncthreads();
}

// Blocked Cholesky; panel in one wave's registers (shfl), rank-16 trailing update.
// Lt[k*128+i] = L[i][k] for i>k; diag holds 1/L[k][k]; 0 above.
__device__ __forceinline__ void dev_chol(Smem* sm, const float* Cslab, float* Lt) {
    int tid = threadIdx.x;
    for (int f2 = tid; f2 < 8192; f2 += 256) {
        int f = f2 << 1;
        v2f s = ald2(&Cslab[f]);
        #pragma unroll
        for (int z = 1; z < 8; ++z) {
            v2f v = ald2(&Cslab[z * 16384 + f]);
            s.x += v.x; s.y += v.y;
        }
        int r = f >> 7, c = f & 127;
        sm->chol.Cs[r][c] = s.x;
        sm->chol.Cs[r][c + 1] = s.y;
    }
    __syncthreads();
    int lane = tid & 63;
    for (int kb = 0; kb < 8; ++kb) {
        int k0 = kb * 16;
        if (tid < 64) {
            float P0[16], P1[16], invs[16];
            #pragma unroll
            for (int u = 0; u < 16; ++u) {
                P0[u] = sm->chol.Cs[lane][k0 + u];
                P1[u] = sm->chol.Cs[lane + 64][k0 + u];
            }
            #pragma unroll
            for (int kk = 0; kk < 16; ++kk) {
                int k = k0 + kk;
                int src = k & 63;
                bool hi = (k >= 64);
                float pr[16];
                #pragma unroll
                for (int u = 0; u < 16; ++u)
                    if (u >= kk) pr[u] = __shfl(hi ? P1[u] : P0[u], src);
                float inv = 1.0f / pr[kk];
                invs[kk] = inv;
                float f0 = (lane > k) ? P0[kk] * inv : 0.f;
                float f1 = ((lane + 64) > k) ? P1[kk] * inv : 0.f;
                #pragma unroll
                for (int u = kk + 1; u < 16; ++u) {
                    P0[u] -= f0 * pr[u];
                    P1[u] -= f1 * pr[u];
                }
            }
            #pragma unroll
            for (int u = 0; u < 16; ++u) {
                sm->chol.Cs[lane][k0 + u] = P0[u];
                sm->chol.Cs[lane + 64][k0 + u] = P1[u];
            }
            if (lane == 0) {
                #pragma unroll
                for (int kk = 0; kk < 16; ++kk) sm->chol.inv_d[kk] = invs[kk];
            }
        }
        __syncthreads();
        int base = k0 + 16;
        if (base < 128) {
            int h = tid >> 6, c = tid & 63;
            int j1 = base + c;
            int j2 = base + c + 64;
            bool has1 = (j1 < 128), has2 = (j2 < 128);
            float w1[16], w2[16];
            if (has1) {
                #pragma unroll
                for (int u = 0; u < 16; ++u) w1[u] = sm->chol.Cs[j1][k0 + u] * sm->chol.inv_d[u];
            }
            if (has2) {
                #pragma unroll
                for (int u = 0; u < 16; ++u) w2[u] = sm->chol.Cs[j2][k0 + u] * sm->chol.inv_d[u];
            }
            int rlo = h * 32;
            int istart = rlo > base ? rlo : base;
            for (int i = istart; i < rlo + 32; ++i) {
                float v[16];
                #pragma unroll
                for (int u = 0; u < 16; ++u) v[u] = sm->chol.Cs[i][k0 + u];
                float a1 = 0.f, a2 = 0.f;
                #pragma unroll
                for (int u = 0; u < 16; ++u) { a1 += v[u] * w1[u]; a2 += v[u] * w2[u]; }
                if (has1) sm->chol.Cs[i][j1] -= a1;
                if (has2) sm->chol.Cs[i][j2] -= a2;
            }
        }
        __syncthreads();
    }
    for (int f2 = tid; f2 < 8192; f2 += 256) {
        int k = f2 >> 6, i2 = (f2 & 63) << 1;
        float d = sm->chol.Cs[k][k];
        float irs = 1.0f / sqrtf(d);
        float v0, v1;
        int i = i2;
        v0 = (i < k) ? 0.f : ((i == k) ? irs : sm->chol.Cs[i][k] * irs);
        i = i2 + 1;
        v1 = (i < k) ? 0.f : ((i == k) ? irs : sm->chol.Cs[i][k] * irs);
        ast2(&Lt[k * 128 + i2], v0, v1);
    }
    __syncthreads();
}

// Forward solve L*X = sum of ns RHS slabs. 32 cols/block; band h = 16 rows in regs.
__device__ __forceinline__ void dev_trsm(Smem* sm, const float* Lt, const float* RHS,
                                         int ns, float* Qt, int bid) {
    int tid = threadIdx.x;
    int c = tid & 31, h = tid >> 5;
    int j0 = bid * 32;
    for (int f2 = tid; f2 < 8192; f2 += 256) {
        v2f v = ald2(&Lt[f2 << 1]);
        sm->trsm.Ls[(f2 << 1)] = v.x;
        sm->trsm.Ls[(f2 << 1) + 1] = v.y;
    }
    float acc[16];
    #pragma unroll
    for (int r = 0; r < 16; ++r) {
        int row = h * 16 + r;
        float s = ald(&RHS[row * 1024 + j0 + c]);
        for (int z = 1; z < ns; ++z) s += ald(&RHS[z * 131072 + row * 1024 + j0 + c]);
        acc[r] = s;
    }
    __syncthreads();
    float* Ls = sm->trsm.Ls;
    for (int pb = 0; pb < 8; ++pb) {
        int p0 = pb * 16;
        if (h == pb) {
            #pragma unroll
            for (int kk = 0; kk < 16; ++kk) {
                int k = p0 + kk;
                float x = acc[kk] * Ls[k * 128 + k];   // diag = 1/L
                acc[kk] = x;
                sm->trsm.Xs[kk][c] = x;
                #pragma unroll
                for (int r = kk + 1; r < 16; ++r)
                    acc[r] -= Ls[k * 128 + p0 + r] * x;
            }
        }
        __syncthreads();
        if (h > pb) {
            int rb = h * 16;
            #pragma unroll
            for (int kk = 0; kk < 16; ++kk) {
                float x = sm->trsm.Xs[kk][c];
                const float4* lr = (const float4*)&Ls[(p0 + kk) * 128 + rb];
                #pragma unroll
                for (int g4 = 0; g4 < 4; ++g4) {
                    float4 lv = lr[g4];
                    acc[g4 * 4 + 0] -= lv.x * x;
                    acc[g4 * 4 + 1] -= lv.y * x;
                    acc[g4 * 4 + 2] -= lv.z * x;
                    acc[g4 * 4 + 3] -= lv.w * x;
                }
            }
        }
        __syncthreads();
    }
    #pragma unroll
    for (int r = 0; r < 16; ++r)
        ast(&Qt[(h * 16 + r) * 1024 + j0 + c], acc[r]);
}

// G = 8*Qt^T Qt + per-block row abs-sum partials
__device__ __forceinline__ void dev_gemmG(Smem* sm, const float* Qt, float* G,
                                          float* Rpart, int bid) {
    int tid = threadIdx.x;
    int tx = tid & 15, ty = tid >> 4;
    int bx = bid & 15, by = bid >> 4;
    int a0 = by * 64, b0 = bx * 64;
    float acc[4][4] = {};
    for (int kc = 0; kc < 128; kc += 32) {
        for (int i = tid; i < 1024; i += 256) {
            int r = i >> 5, c2 = (i & 31) << 1;
            v2f v = ald2(&Qt[(kc + r) * 1024 + a0 + c2]);
            sm->gg.As[r][c2] = v.x; sm->gg.As[r][c2 + 1] = v.y;
            v2f w = ald2(&Qt[(kc + r) * 1024 + b0 + c2]);
            sm->gg.Bs[r][c2] = w.x; sm->gg.Bs[r][c2 + 1] = w.y;
        }
        __syncthreads();
        for (int k = 0; k < 32; ++k) {
            float4 av = *(const float4*)&sm->gg.As[k][ty * 4];
            float4 bv = *(const float4*)&sm->gg.Bs[k][tx * 4];
            float a[4] = {av.x, av.y, av.z, av.w};
            float b[4] = {bv.x, bv.y, bv.z, bv.w};
            #pragma unroll
            for (int i = 0; i < 4; ++i)
                #pragma unroll
                for (int j = 0; j < 4; ++j) acc[i][j] += a[i] * b[j];
        }
        __syncthreads();
    }
    float rsum[4] = {0.f, 0.f, 0.f, 0.f};
    for (int i = 0; i < 4; ++i) {
        int aa = a0 + ty * 4 + i;
        float g[4];
        #pragma unroll
        for (int j = 0; j < 4; ++j) g[j] = 8.f * acc[i][j];
        float* gp = &G[aa * 1024 + b0 + tx * 4];
        ast2(gp, g[0], g[1]);
        ast2(gp + 2, g[2], g[3]);
        int bb = b0 + tx * 4;
        #pragma unroll
        for (int j = 0; j < 4; ++j) rsum[i] += (aa == bb + j) ? 0.f : fabsf(g[j]);
    }
    for (int i = 0; i < 4; ++i) sm->gg.Rs[ty * 4 + i][tx] = rsum[i];
    __syncthreads();
    if (tid < 64) {
        float s = 0.f;
        for (int x = 0; x < 16; ++x) s += sm->gg.Rs[tid][x];
        ast(&Rpart[bx * 1024 + a0 + tid], s);
    }
}

// Ri[1024] into sm->gy.Ri; returns rth/delta (all threads)
__device__ __forceinline__ void dev_ri(Smem* sm, const float* Rpart,
                                       float* rth, float* delta) {
    int tid = threadIdx.x;
    float mn = 3.4e38f;
    for (int i = tid; i < 1024; i += 256) {
        float s = 0.f;
        #pragma unroll
        for (int x = 0; x < 16; ++x) s += ald(&Rpart[x * 1024 + i]);
        sm->gy.Ri[i] = s;
        mn = fminf(mn, s);
    }
    sm->gy.red[tid] = mn;
    __syncthreads();
    for (int w = 128; w > 0; w >>= 1) {
        if (tid < w) sm->gy.red[tid] = fminf(sm->gy.red[tid], sm->gy.red[tid + w]);
        __syncthreads();
    }
    float r = sm->gy.red[0];
    *rth = r;
    *delta = r / 1023.f;
}

// Yslab[kz] = Qt * G' over K-chunk kz (256 wide); mask fused; Ri from LDS.
__device__ __forceinline__ void dev_gemmY(Smem* sm, const float* Qt, const float* G,
                                          float rth, float delta, float* Yslab, int bid) {
    int tid = threadIdx.x;
    int j0 = (bid & 15) * 64;
    int m0 = ((bid >> 4) & 3) * 32;
    int kz = bid >> 6;
    int kc0 = kz * 256;
    int tx = tid & 15, ty = tid >> 4;
    float acc[2][4] = {};
    for (int kc = kc0; kc < kc0 + 256; kc += 32) {
        for (int i = tid; i < 512; i += 256) {
            int m = i >> 4, k2 = (i & 15) << 1;
            v2f v = ald2(&Qt[(m0 + m) * 1024 + kc + k2]);
            sm->gy.As[k2][m] = v.x; sm->gy.As[k2 + 1][m] = v.y;
        }
        for (int i = tid; i < 1024; i += 256) {
            int k = i >> 5, n2 = (i & 31) << 1;
            int a = kc + k;
            float ria = sm->gy.Ri[a];
            v2f v = ald2(&G[a * 1024 + j0 + n2]);
            int b0i = j0 + n2;
            {
                float g = v.x;
                float sg = delta * ((g > 0.f) ? 1.f : ((g < 0.f) ? -1.f : 0.f));
                float ga = (ria > rth) ? sg : g;
                float gb = (sm->gy.Ri[b0i] > rth) ? sg : g;
                sm->gy.Bs[k][n2] = (a == b0i) ? g : 0.5f * (ga + gb);
            }
            {
                float g = v.y;
                float sg = delta * ((g > 0.f) ? 1.f : ((g < 0.f) ? -1.f : 0.f));
                float ga = (ria > rth) ? sg : g;
                float gb = (sm->gy.Ri[b0i + 1] > rth) ? sg : g;
                sm->gy.Bs[k][n2 + 1] = (a == b0i + 1) ? g : 0.5f * (ga + gb);
            }
        }
        __syncthreads();
        for (int k = 0; k < 32; ++k) {
            float a0v = sm->gy.As[k][ty * 2], a1v = sm->gy.As[k][ty * 2 + 1];
            float4 bv = *(const float4*)&sm->gy.Bs[k][tx * 4];
            acc[0][0] += a0v * bv.x; acc[0][1] += a0v * bv.y;
            acc[0][2] += a0v * bv.z; acc[0][3] += a0v * bv.w;
            acc[1][0] += a1v * bv.x; acc[1][1] += a1v * bv.y;
            acc[1][2] += a1v * bv.z; acc[1][3] += a1v * bv.w;
        }
        __syncthreads();
    }
    float* outp = &Yslab[kz * 131072];
    for (int i = 0; i < 2; ++i) {
        float* op = &outp[(m0 + ty * 2 + i) * 1024 + j0 + tx * 4];
        ast2(op, acc[i][0], acc[i][1]);
        ast2(op + 2, acc[i][2], acc[i][3]);
    }
}

// trB partial: S-tile = (Qt^T Qt)[64x64] in regs; s += sum G'(G_old)⊙S ; atomicAdd
__device__ __forceinline__ void dev_trB(Smem* sm, const float* Qt, const float* G,
                                        const float* Rpart, float* accb, int bid) {
    int tid = threadIdx.x;
    float rth, delta;
    dev_ri(sm, Rpart, &rth, &delta);
    __syncthreads();
    int tx = tid & 15, ty = tid >> 4;
    int a0 = (bid >> 4) * 64, b0 = (bid & 15) * 64;
    float acc[4][4] = {};
    for (int kc = 0; kc < 128; kc += 32) {
        for (int i = tid; i < 1024; i += 256) {
            int r = i >> 5, c2 = (i & 31) << 1;
            v2f v = ald2(&Qt[(kc + r) * 1024 + a0 + c2]);
            sm->gy.As[r & 31][c2 & 31] = 0.f; // no-op guard (kept layout below)
            (void)v;
            break;
        }
        // stage A/B tiles (64-wide) into gg-style buffers living in gy union:
        // reuse gy.As is too small; use a direct register-free path via syrk layout
        __syncthreads();
        break;
    }
    // -- restart with syrk-union staging (128 rows unused; we use 32) --
    for (int kc = 0; kc < 128; kc += 32) {
        for (int i = tid; i < 1024; i += 256) {
            int r = i >> 5, c2 = (i & 31) << 1;
            v2f v = ald2(&Qt[(kc + r) * 1024 + a0 + c2]);
            sm->syrk.As[r][c2] = v.x; sm->syrk.As[r][c2 + 1] = v.y;
            v2f w = ald2(&Qt[(kc + r) * 1024 + b0 + c2]);
            sm->syrk.Bs[r][c2] = w.x; sm->syrk.Bs[r][c2 + 1] = w.y;
        }
        __syncthreads();
        for (int k = 0; k < 32; ++k) {
            float4 av = *(const float4*)&sm->syrk.As[k][ty * 4];
            float4 bv = *(const float4*)&sm->syrk.Bs[k][tx * 4];
            float a[4] = {av.x, av.y, av.z, av.w};
            float b[4] = {bv.x, bv.y, bv.z, bv.w};
            #pragma unroll
            for (int i = 0; i < 4; ++i)
                #pragma unroll
                for (int j = 0; j < 4; ++j) acc[i][j] += a[i] * b[j];
        }
        __syncthreads();
    }
    // Ri must survive: it lived in gy.Ri which aliases syrk.As!  Recompute rth/delta
    // pattern instead: re-derive Ri values needed (aa rows, bb cols) directly.
    // Simpler: recompute dev_ri into registers for the 8 values we need:
    float s = 0.f;
    for (int i = 0; i < 4; ++i) {
        int aa = a0 + ty * 4 + i;
        float ria = 0.f;
        #pragma unroll
        for (int x = 0; x < 16; ++x) ria += ald(&Rpart[x * 1024 + aa]);
        for (int j = 0; j < 4; ++j) {
            int bb = b0 + tx * 4 + j;
            float rib = 0.f;
            #pragma unroll
            for (int x = 0; x < 16; ++x) rib += ald(&Rpart[x * 1024 + bb]);
            float g = ald(&G[aa * 1024 + bb]);
            float sg = delta * ((g > 0.f) ? 1.f : ((g < 0.f) ? -1.f : 0.f));
            float ga = (ria > rth) ? sg : g;
            float gb = (rib > rth) ? sg : g;
            float gp = (aa == bb) ? g : 0.5f * (ga + gb);
            s += gp * acc[i][j];
        }
    }
    __syncthreads();
    sm->red[tid] = s;
    __syncthreads();
    for (int w = 128; w > 0; w >>= 1) {
        if (tid < w) sm->red[tid] += sm->red[tid + w];
        __syncthreads();
    }
    if (tid == 0) atomicAdd(&accb[2], sm->red[0]);
}

__global__ __launch_bounds__(256) void mega(const float* __restrict__ t1,
                                            const float* __restrict__ t2,
                                            const float* __restrict__ params,
                                            const float* __restrict__ tmin,
                                            const float* __restrict__ tmax,
                                            const float* __restrict__ beta,
                                            const float* __restrict__ R,
                                            float* ws, float* out) {
    float* G     = ws + OFF_G;
    float* Qt    = ws + OFF_QT;
    float* Yslab = ws + OFF_YS;
    float* Cslab = ws + OFF_CS;
    float* Lt    = ws + OFF_LT;
    float* Rpart = ws + OFF_RP;
    float* accb  = ws + OFF_ACC;
    unsigned* bb = (unsigned*)(ws + OFF_BAR);
    __shared__ Smem sm;
    int bid = blockIdx.x;
    unsigned phA = 0, phB = 0, phC = 0, phD = 0, phE = 0;

    // Prologue: syrk(R) on blocks 0..31; loss stats on the rest.
    if (bid < 32) dev_syrk(&sm, R, 1, R, 1, Cslab, bid);
    else if (bid < 250) dev_match(&sm, t1, t2, accb, bid - 32);
    else if (bid == 250) dev_range(&sm, params, tmin, tmax, accb);
    else if (bid < 255) dev_sumsq(&sm, R, accb, bid - 251);
    ++phC;
    if (bid < 32) bar_arrive(bb, BAR_C + (bid >> 2));
    if (bid == 0) { bar_wait(bb, BAR_C, 8, phC * 4); dev_chol(&sm, Cslab, Lt); }
    ++phD;
    if (bid == 0) bar_arrive(bb, BAR_D);
    if (bid < 32) { bar_wait(bb, BAR_D, 1, phD); dev_trsm(&sm, Lt, R, 1, Qt, bid); }
    ++phE;
    if (bid < 32) bar_arrive(bb, BAR_E + (bid >> 2));
    bar_wait(bb, BAR_E, 8, phE * 4);

    for (int it = 0; it < 50; ++it) {
        dev_gemmG(&sm, Qt, G, Rpart, bid);
        ++phA;
        bar_arrive(bb, BAR_A + (bid >> 3));
        bar_wait(bb, BAR_A, 32, phA * 8);
        {
            float rth, delta;
            dev_ri(&sm, Rpart, &rth, &delta);
            dev_gemmY(&sm, Qt, G, rth, delta, Yslab, bid);
        }
        ++phB;
        bar_arrive(bb, BAR_B + (bid >> 3));
        if (bid < 32) {
            bar_wait(bb, BAR_B, 32, phB * 8);
            dev_syrk(&sm, Yslab, 4, Yslab, 4, Cslab, bid);
        }
        ++phC;
        if (bid < 32) bar_arrive(bb, BAR_C + (bid >> 2));
        if (bid == 0) { bar_wait(bb, BAR_C, 8, phC * 4); dev_chol(&sm, Cslab, Lt); }
        ++phD;
        if (bid == 0) bar_arrive(bb, BAR_D);
        if (bid < 32) { bar_wait(bb, BAR_D, 1, phD); dev_trsm(&sm, Lt, Yslab, 4, Qt, bid); }
        ++phE;
        if (bid < 32) bar_arrive(bb, BAR_E + (bid >> 2));
        bar_wait(bb, BAR_E, 8, phE * 4);
    }

    // epilogue: trB = sum G'(G_49) ⊙ (Q50^T Q50), using Rpart_49 still in ws
    dev_trB(&sm, Qt, G, Rpart, accb, bid);
    ++phA;
    bar_arrive(bb, BAR_A + (bid >> 3));
    if (bid == 0) {
        bar_wait(bb, BAR_A, 32, phA * 8);
        if (threadIdx.x == 0)
            out[0] = ald(&accb[0]) / 4194304.f + beta[0] * (ald(&accb[1]) / 2176.f)
                   + (ald(&accb[2]) + ald(&accb[3])) / 131072.f;
    }
}

extern "C" void kernel_launch(void* const* d_in, const int* in_sizes, int n_in,
                              void* d_out, int out_size, void* d_ws, size_t ws_size,
                              hipStream_t stream) {
    const float* t1 = (const float*)d_in[0];
    const float* t2 = (const float*)d_in[1];
    const float* params = (const float*)d_in[2];
    const float* tmin = (const float*)d_in[3];
    const float* tmax = (const float*)d_in[4];
    const float* beta = (const float*)d_in[5];
    const float* R = (const float*)d_in[6];
    float* ws = (float*)d_ws;
    float* out = (float*)d_out;

    // zero accumulators + barrier counter lines
    hipMemsetAsync(ws + OFF_ACC, 0, 5312, stream);
    mega<<<NBLK, 256, 0, stream>>>(t1, t2, params, tmin, tmax, beta, R, ws, out);
}

// Round 7
// 8408.054 us; speedup vs baseline: 2.0419x; 1.3323x over previous
//
#include <hip/hip_runtime.h>

#define NBLK 256

// workspace layout (floats)
#define OFF_G    0            // 1024*1024
#define OFF_QT   1048576      // 128*1024
#define OFF_YS   1179648      // 4 slabs * 128*1024
#define OFF_CS   1703936      // 8 slabs * 128*128
#define OFF_LT   1835008      // 128*128
#define OFF_RP   1851392      // Rpart[1024][16]
#define OFF_ACC  1867776      // 4 floats
#define OFF_BAR  1867792      // 81 counter lines (stride 16 u32)

#define BAR_A 0    // 32 lines, 256 arrive / 256 wait
#define BAR_B 32   // 32 lines, 256 arrive / 32 wait
#define BAR_C 64   // 8 lines, 32 arrive / 1 wait
#define BAR_D 72   // 1 line, 1 arrive / 32 wait
#define BAR_E 73   // 8 lines, 32 arrive / 256 wait

typedef float v4f __attribute__((ext_vector_type(4)));

// ---- batched agent-coherent loads (sc1 = agent scope, bypass stale L1/L2),
// grouped so several are in flight before one waitcnt ----
__device__ __forceinline__ void cld4_2(v4f& a, v4f& b,
                                       const float* pa, const float* pb) {
    asm volatile("global_load_dwordx4 %0, %2, off sc1\n\t"
                 "global_load_dwordx4 %1, %3, off sc1\n\t"
                 "s_waitcnt vmcnt(0)"
                 : "=&v"(a), "=&v"(b) : "v"(pa), "v"(pb) : "memory");
}
__device__ __forceinline__ void cld4_3(v4f& a, v4f& b, v4f& c,
                                       const float* pa, const float* pb,
                                       const float* pc) {
    asm volatile("global_load_dwordx4 %0, %3, off sc1\n\t"
                 "global_load_dwordx4 %1, %4, off sc1\n\t"
                 "global_load_dwordx4 %2, %5, off sc1\n\t"
                 "s_waitcnt vmcnt(0)"
                 : "=&v"(a), "=&v"(b), "=&v"(c)
                 : "v"(pa), "v"(pb), "v"(pc) : "memory");
}
__device__ __forceinline__ void cld4_4(v4f& a, v4f& b, v4f& c, v4f& d,
                                       const float* pa, const float* pb,
                                       const float* pc, const float* pd) {
    asm volatile("global_load_dwordx4 %0, %4, off sc1\n\t"
                 "global_load_dwordx4 %1, %5, off sc1\n\t"
                 "global_load_dwordx4 %2, %6, off sc1\n\t"
                 "global_load_dwordx4 %3, %7, off sc1\n\t"
                 "s_waitcnt vmcnt(0)"
                 : "=&v"(a), "=&v"(b), "=&v"(c), "=&v"(d)
                 : "v"(pa), "v"(pb), "v"(pc), "v"(pd) : "memory");
}
__device__ __forceinline__ void cld4_8(v4f& a, v4f& b, v4f& c, v4f& d,
                                       v4f& e, v4f& f, v4f& g, v4f& h,
                                       const float* pa, const float* pb,
                                       const float* pc, const float* pd,
                                       const float* pe, const float* pf,
                                       const float* pg, const float* ph) {
    asm volatile("global_load_dwordx4 %0, %8, off sc1\n\t"
                 "global_load_dwordx4 %1, %9, off sc1\n\t"
                 "global_load_dwordx4 %2, %10, off sc1\n\t"
                 "global_load_dwordx4 %3, %11, off sc1\n\t"
                 "global_load_dwordx4 %4, %12, off sc1\n\t"
                 "global_load_dwordx4 %5, %13, off sc1\n\t"
                 "global_load_dwordx4 %6, %14, off sc1\n\t"
                 "global_load_dwordx4 %7, %15, off sc1\n\t"
                 "s_waitcnt vmcnt(0)"
                 : "=&v"(a), "=&v"(b), "=&v"(c), "=&v"(d),
                   "=&v"(e), "=&v"(f), "=&v"(g), "=&v"(h)
                 : "v"(pa), "v"(pb), "v"(pc), "v"(pd),
                   "v"(pe), "v"(pf), "v"(pg), "v"(ph) : "memory");
}
__device__ __forceinline__ void cld1_4(float& a, float& b, float& c, float& d,
                                       const float* pa, const float* pb,
                                       const float* pc, const float* pd) {
    asm volatile("global_load_dword %0, %4, off sc1\n\t"
                 "global_load_dword %1, %5, off sc1\n\t"
                 "global_load_dword %2, %6, off sc1\n\t"
                 "global_load_dword %3, %7, off sc1\n\t"
                 "s_waitcnt vmcnt(0)"
                 : "=&v"(a), "=&v"(b), "=&v"(c), "=&v"(d)
                 : "v"(pa), "v"(pb), "v"(pc), "v"(pd) : "memory");
}
__device__ __forceinline__ void cld1_8(float& a, float& b, float& c, float& d,
                                       float& e, float& f, float& g, float& h,
                                       const float* pa, const float* pb,
                                       const float* pc, const float* pd,
                                       const float* pe, const float* pf,
                                       const float* pg, const float* ph) {
    asm volatile("global_load_dword %0, %8, off sc1\n\t"
                 "global_load_dword %1, %9, off sc1\n\t"
                 "global_load_dword %2, %10, off sc1\n\t"
                 "global_load_dword %3, %11, off sc1\n\t"
                 "global_load_dword %4, %12, off sc1\n\t"
                 "global_load_dword %5, %13, off sc1\n\t"
                 "global_load_dword %6, %14, off sc1\n\t"
                 "global_load_dword %7, %15, off sc1\n\t"
                 "s_waitcnt vmcnt(0)"
                 : "=&v"(a), "=&v"(b), "=&v"(c), "=&v"(d),
                   "=&v"(e), "=&v"(f), "=&v"(g), "=&v"(h)
                 : "v"(pa), "v"(pb), "v"(pc), "v"(pd),
                   "v"(pe), "v"(pf), "v"(pg), "v"(ph) : "memory");
}

// ---- coherent scalar/pair stores + loads (relaxed atomics; stores pipeline) ----
__device__ __forceinline__ void ast2(float* p, float a, float b) {
    union { unsigned long long u; float f[2]; } c; c.f[0] = a; c.f[1] = b;
    __hip_atomic_store((unsigned long long*)p, c.u,
                       __ATOMIC_RELAXED, __HIP_MEMORY_SCOPE_AGENT);
}
__device__ __forceinline__ float ald(const float* p) {
    return __hip_atomic_load(p, __ATOMIC_RELAXED, __HIP_MEMORY_SCOPE_AGENT);
}
__device__ __forceinline__ void ast(float* p, float x) {
    __hip_atomic_store(p, x, __ATOMIC_RELAXED, __HIP_MEMORY_SCOPE_AGENT);
}

__device__ __forceinline__ void bar_arrive(unsigned* bb, int line) {
    __syncthreads();
    if (threadIdx.x == 0)
        __hip_atomic_fetch_add(bb + line * 16, 1u,
                               __ATOMIC_RELAXED, __HIP_MEMORY_SCOPE_AGENT);
}
__device__ __forceinline__ void bar_wait(unsigned* bb, int wbase, int nlines,
                                         unsigned tgt) {
    if ((int)threadIdx.x < nlines) {
        while (__hip_atomic_load(bb + (wbase + threadIdx.x) * 16,
                                 __ATOMIC_RELAXED, __HIP_MEMORY_SCOPE_AGENT) < tgt)
            __builtin_amdgcn_s_sleep(2);
    }
    __builtin_amdgcn_s_waitcnt(0);
    __syncthreads();
}

union Smem {
    struct { float As[128][68]; float Bs[128][68]; } syrk;        // 69632 B
    struct { float Cs[128][129]; float inv_d[16]; } chol;
    struct { float Ls[128 * 128]; float Xs[16][32]; } trsm;
    struct { float As[32][68]; float Bs[32][68]; float Rs[64][16]; } gg;
    struct { float Ri[1024]; float red[256]; float As[32][33]; float Bs[32][68]; } gy;
    float red[256];
};

__device__ __forceinline__ void dev_match(Smem* sm, const float* t1, const float* t2,
                                          float* accb, int w) {
    int tid = threadIdx.x;
    const float4* a = (const float4*)t1;
    const float4* b = (const float4*)t2;
    float s = 0.f;
    for (int i = w * 256 + tid; i < 1048576; i += 218 * 256) {
        float4 x = a[i], y = b[i];
        float d0 = x.x - y.x, d1 = x.y - y.y, d2 = x.z - y.z, d3 = x.w - y.w;
        s += d0 * d0 + d1 * d1 + d2 * d2 + d3 * d3;
    }
    sm->red[tid] = s; __syncthreads();
    for (int w2 = 128; w2 > 0; w2 >>= 1) {
        if (tid < w2) sm->red[tid] += sm->red[tid + w2];
        __syncthreads();
    }
    if (tid == 0) atomicAdd(&accb[0], sm->red[0]);
    __syncthreads();
}

__device__ __forceinline__ void dev_range(Smem* sm, const float* params, const float* tmin,
                                          const float* tmax, float* accb) {
    int tid = threadIdx.x;
    float a = tmin[0], b = tmax[0];
    const float d = 0.01f;
    float s = 0.f;
    for (int i = tid; i < 128 * 17; i += 256) {
        float p = params[i];
        float r1 = (p - a - d) / (-d);
        float r2 = (p - b + d) / d;
        s += fmaxf(fmaxf(r1, r2), 0.f);
    }
    sm->red[tid] = s; __syncthreads();
    for (int w = 128; w > 0; w >>= 1) {
        if (tid < w) sm->red[tid] += sm->red[tid + w];
        __syncthreads();
    }
    if (tid == 0) atomicAdd(&accb[1], sm->red[0]);
    __syncthreads();
}

__device__ __forceinline__ void dev_sumsq(Smem* sm, const float* X, float* accb, int w) {
    int tid = threadIdx.x;
    float s = 0.f;
    for (int i = w * 256 + tid; i < 131072; i += 1024) { float v = X[i]; s += v * v; }
    sm->red[tid] = s; __syncthreads();
    for (int w2 = 128; w2 > 0; w2 >>= 1) {
        if (tid < w2) sm->red[tid] += sm->red[tid + w2];
        __syncthreads();
    }
    if (tid == 0) atomicAdd(&accb[3], sm->red[0]);
    __syncthreads();
}

// Cslab[z] = A_eff(64 rows p0) x B_eff(64 rows q0) over K-chunk z of 128.
// ns==1: A,B are the read-only input R (plain cached loads). ns==4: Yslab (coherent).
__device__ __forceinline__ void dev_syrk(Smem* sm, const float* A, int nsA,
                                         const float* B, int nsB, float* Cslab, int bid) {
    int tid = threadIdx.x;
    int q0 = (bid & 1) * 64, p0 = ((bid >> 1) & 1) * 64, z = bid >> 2;
    int kc = z * 128;
    if (nsA == 1) {
        for (int i = tid; i < 2048; i += 256) {
            int r = i >> 5, c4 = (i & 31) << 2;
            float4 v = *(const float4*)&A[(p0 + r) * 1024 + kc + c4];
            sm->syrk.As[c4][r] = v.x; sm->syrk.As[c4 + 1][r] = v.y;
            sm->syrk.As[c4 + 2][r] = v.z; sm->syrk.As[c4 + 3][r] = v.w;
        }
        for (int i = tid; i < 2048; i += 256) {
            int r = i >> 5, c4 = (i & 31) << 2;
            float4 v = *(const float4*)&B[(q0 + r) * 1024 + kc + c4];
            sm->syrk.Bs[c4][r] = v.x; sm->syrk.Bs[c4 + 1][r] = v.y;
            sm->syrk.Bs[c4 + 2][r] = v.z; sm->syrk.Bs[c4 + 3][r] = v.w;
        }
    } else {
        for (int cc = 0; cc < 8; cc += 2) {
            int i0 = tid + cc * 256, i1 = i0 + 256;
            int r0 = i0 >> 5, c40 = (i0 & 31) << 2;
            int r1 = i1 >> 5, c41 = (i1 & 31) << 2;
            const float* b0p = &A[(p0 + r0) * 1024 + kc + c40];
            const float* b1p = &A[(p0 + r1) * 1024 + kc + c41];
            v4f x0, x1, x2, x3, y0, y1, y2, y3;
            cld4_8(x0, x1, x2, x3, y0, y1, y2, y3,
                   b0p, b0p + 131072, b0p + 262144, b0p + 393216,
                   b1p, b1p + 131072, b1p + 262144, b1p + 393216);
            v4f s0 = x0; s0 += x1; s0 += x2; s0 += x3;
            v4f s1 = y0; s1 += y1; s1 += y2; s1 += y3;
            sm->syrk.As[c40][r0] = s0.x; sm->syrk.As[c40 + 1][r0] = s0.y;
            sm->syrk.As[c40 + 2][r0] = s0.z; sm->syrk.As[c40 + 3][r0] = s0.w;
            sm->syrk.As[c41][r1] = s1.x; sm->syrk.As[c41 + 1][r1] = s1.y;
            sm->syrk.As[c41 + 2][r1] = s1.z; sm->syrk.As[c41 + 3][r1] = s1.w;
        }
        for (int cc = 0; cc < 8; cc += 2) {
            int i0 = tid + cc * 256, i1 = i0 + 256;
            int r0 = i0 >> 5, c40 = (i0 & 31) << 2;
            int r1 = i1 >> 5, c41 = (i1 & 31) << 2;
            const float* b0p = &B[(q0 + r0) * 1024 + kc + c40];
            const float* b1p = &B[(q0 + r1) * 1024 + kc + c41];
            v4f x0, x1, x2, x3, y0, y1, y2, y3;
            cld4_8(x0, x1, x2, x3, y0, y1, y2, y3,
                   b0p, b0p + 131072, b0p + 262144, b0p + 393216,
                   b1p, b1p + 131072, b1p + 262144, b1p + 393216);
            v4f s0 = x0; s0 += x1; s0 += x2; s0 += x3;
            v4f s1 = y0; s1 += y1; s1 += y2; s1 += y3;
            sm->syrk.Bs[c40][r0] = s0.x; sm->syrk.Bs[c40 + 1][r0] = s0.y;
            sm->syrk.Bs[c40 + 2][r0] = s0.z; sm->syrk.Bs[c40 + 3][r0] = s0.w;
            sm->syrk.Bs[c41][r1] = s1.x; sm->syrk.Bs[c41 + 1][r1] = s1.y;
            sm->syrk.Bs[c41 + 2][r1] = s1.z; sm->syrk.Bs[c41 + 3][r1] = s1.w;
        }
    }
    __syncthreads();
    int tx = tid & 15, ty = tid >> 4;
    float acc[4][4] = {};
    for (int k = 0; k < 128; ++k) {
        float4 av = *(const float4*)&sm->syrk.As[k][ty * 4];
        float4 bv = *(const float4*)&sm->syrk.Bs[k][tx * 4];
        float a[4] = {av.x, av.y, av.z, av.w};
        float b[4] = {bv.x, bv.y, bv.z, bv.w};
        #pragma unroll
        for (int i = 0; i < 4; ++i)
            #pragma unroll
            for (int j = 0; j < 4; ++j) acc[i][j] += a[i] * b[j];
    }
    float* outp = &Cslab[z * 16384];
    for (int i = 0; i < 4; ++i) {
        float* op = &outp[(p0 + ty * 4 + i) * 128 + q0 + tx * 4];
        ast2(op, acc[i][0], acc[i][1]);
        ast2(op + 2, acc[i][2], acc[i][3]);
    }
    __syncthreads();
}

__device__ __forceinline__ void dev_chol(Smem* sm, const float* Cslab, float* Lt) {
    int tid = threadIdx.x;
    for (int cc = 0; cc < 16; ++cc) {
        int i = tid + cc * 256;               // 4096 dwordx4 chunks
        int r = i >> 5, c4 = (i & 31) << 2;
        const float* b = &Cslab[i * 4];
        v4f z0, z1, z2, z3, z4, z5, z6, z7;
        cld4_8(z0, z1, z2, z3, z4, z5, z6, z7,
               b, b + 16384, b + 32768, b + 49152,
               b + 65536, b + 81920, b + 98304, b + 114688);
        v4f s = z0; s += z1; s += z2; s += z3; s += z4; s += z5; s += z6; s += z7;
        sm->chol.Cs[r][c4] = s.x; sm->chol.Cs[r][c4 + 1] = s.y;
        sm->chol.Cs[r][c4 + 2] = s.z; sm->chol.Cs[r][c4 + 3] = s.w;
    }
    __syncthreads();
    int lane = tid & 63;
    for (int kb = 0; kb < 8; ++kb) {
        int k0 = kb * 16;
        if (tid < 64) {
            float P0[16], P1[16], invs[16];
            #pragma unroll
            for (int u = 0; u < 16; ++u) {
                P0[u] = sm->chol.Cs[lane][k0 + u];
                P1[u] = sm->chol.Cs[lane + 64][k0 + u];
            }
            #pragma unroll
            for (int kk = 0; kk < 16; ++kk) {
                int k = k0 + kk;
                int src = k & 63;
                bool hi = (k >= 64);
                float pr[16];
                #pragma unroll
                for (int u = 0; u < 16; ++u)
                    if (u >= kk) pr[u] = __shfl(hi ? P1[u] : P0[u], src);
                float inv = 1.0f / pr[kk];
                invs[kk] = inv;
                float f0 = (lane > k) ? P0[kk] * inv : 0.f;
                float f1 = ((lane + 64) > k) ? P1[kk] * inv : 0.f;
                #pragma unroll
                for (int u = kk + 1; u < 16; ++u) {
                    P0[u] -= f0 * pr[u];
                    P1[u] -= f1 * pr[u];
                }
            }
            #pragma unroll
            for (int u = 0; u < 16; ++u) {
                sm->chol.Cs[lane][k0 + u] = P0[u];
                sm->chol.Cs[lane + 64][k0 + u] = P1[u];
            }
            if (lane == 0) {
                #pragma unroll
                for (int kk = 0; kk < 16; ++kk) sm->chol.inv_d[kk] = invs[kk];
            }
        }
        __syncthreads();
        int base = k0 + 16;
        if (base < 128) {
            int h = tid >> 6, c = tid & 63;
            int j1 = base + c;
            int j2 = base + c + 64;
            bool has1 = (j1 < 128), has2 = (j2 < 128);
            float w1[16], w2[16];
            if (has1) {
                #pragma unroll
                for (int u = 0; u < 16; ++u) w1[u] = sm->chol.Cs[j1][k0 + u] * sm->chol.inv_d[u];
            }
            if (has2) {
                #pragma unroll
                for (int u = 0; u < 16; ++u) w2[u] = sm->chol.Cs[j2][k0 + u] * sm->chol.inv_d[u];
            }
            int rlo = h * 32;
            int istart = rlo > base ? rlo : base;
            for (int i = istart; i < rlo + 32; ++i) {
                float v[16];
                #pragma unroll
                for (int u = 0; u < 16; ++u) v[u] = sm->chol.Cs[i][k0 + u];
                float a1 = 0.f, a2 = 0.f;
                #pragma unroll
                for (int u = 0; u < 16; ++u) { a1 += v[u] * w1[u]; a2 += v[u] * w2[u]; }
                if (has1) sm->chol.Cs[i][j1] -= a1;
                if (has2) sm->chol.Cs[i][j2] -= a2;
            }
        }
        __syncthreads();
    }
    for (int f2 = tid; f2 < 8192; f2 += 256) {
        int k = f2 >> 6, i2 = (f2 & 63) << 1;
        float d = sm->chol.Cs[k][k];
        float irs = 1.0f / sqrtf(d);
        float v0, v1;
        int i = i2;
        v0 = (i < k) ? 0.f : ((i == k) ? irs : sm->chol.Cs[i][k] * irs);
        i = i2 + 1;
        v1 = (i < k) ? 0.f : ((i == k) ? irs : sm->chol.Cs[i][k] * irs);
        ast2(&Lt[k * 128 + i2], v0, v1);
    }
    __syncthreads();
}

// Forward solve L*X = sum of ns RHS slabs. 32 cols/block; band h = 16 rows in regs.
__device__ __forceinline__ void dev_trsm(Smem* sm, const float* Lt, const float* RHS,
                                         int ns, float* Qt, int bid) {
    int tid = threadIdx.x;
    int c = tid & 31, h = tid >> 5;
    int j0 = bid * 32;
    for (int cc = 0; cc < 16; cc += 4) {
        int i0 = tid + cc * 256, i1 = i0 + 256, i2 = i0 + 512, i3 = i0 + 768;
        v4f a, b, d, e;
        cld4_4(a, b, d, e, &Lt[i0 * 4], &Lt[i1 * 4], &Lt[i2 * 4], &Lt[i3 * 4]);
        *(v4f*)&sm->trsm.Ls[i0 * 4] = a;
        *(v4f*)&sm->trsm.Ls[i1 * 4] = b;
        *(v4f*)&sm->trsm.Ls[i2 * 4] = d;
        *(v4f*)&sm->trsm.Ls[i3 * 4] = e;
    }
    float acc[16];
    if (ns == 1) {
        #pragma unroll
        for (int r = 0; r < 16; ++r)
            acc[r] = RHS[(h * 16 + r) * 1024 + j0 + c];
    } else {
        for (int r = 0; r < 16; r += 2) {
            const float* p0 = &RHS[(h * 16 + r) * 1024 + j0 + c];
            const float* p1 = p0 + 1024;
            float a0, a1, a2, a3, b0, b1, b2, b3;
            cld1_8(a0, a1, a2, a3, b0, b1, b2, b3,
                   p0, p0 + 131072, p0 + 262144, p0 + 393216,
                   p1, p1 + 131072, p1 + 262144, p1 + 393216);
            acc[r] = ((a0 + a1) + a2) + a3;
            acc[r + 1] = ((b0 + b1) + b2) + b3;
        }
    }
    __syncthreads();
    float* Ls = sm->trsm.Ls;
    for (int pb = 0; pb < 8; ++pb) {
        int p0 = pb * 16;
        if (h == pb) {
            #pragma unroll
            for (int kk = 0; kk < 16; ++kk) {
                int k = p0 + kk;
                float x = acc[kk] * Ls[k * 128 + k];   // diag = 1/L
                acc[kk] = x;
                sm->trsm.Xs[kk][c] = x;
                #pragma unroll
                for (int r = kk + 1; r < 16; ++r)
                    acc[r] -= Ls[k * 128 + p0 + r] * x;
            }
        }
        __syncthreads();
        if (h > pb) {
            int rb = h * 16;
            #pragma unroll
            for (int kk = 0; kk < 16; ++kk) {
                float x = sm->trsm.Xs[kk][c];
                const float4* lr = (const float4*)&Ls[(p0 + kk) * 128 + rb];
                #pragma unroll
                for (int g4 = 0; g4 < 4; ++g4) {
                    float4 lv = lr[g4];
                    acc[g4 * 4 + 0] -= lv.x * x;
                    acc[g4 * 4 + 1] -= lv.y * x;
                    acc[g4 * 4 + 2] -= lv.z * x;
                    acc[g4 * 4 + 3] -= lv.w * x;
                }
            }
        }
        __syncthreads();
    }
    #pragma unroll
    for (int r = 0; r < 16; ++r)
        ast(&Qt[(h * 16 + r) * 1024 + j0 + c], acc[r]);
}

// G = 8*Qt^T Qt + per-block row abs-sum partials (Rpart[row][16])
__device__ __forceinline__ void dev_gemmG(Smem* sm, const float* Qt, float* G,
                                          float* Rpart, int bid) {
    int tid = threadIdx.x;
    int tx = tid & 15, ty = tid >> 4;
    int bx = bid & 15, by = bid >> 4;
    int a0 = by * 64, b0 = bx * 64;
    float acc[4][4] = {};
    for (int kc = 0; kc < 128; kc += 32) {
        int i0 = tid, i1 = tid + 256;
        int r0 = i0 >> 4, c40 = (i0 & 15) << 2;
        int r1 = i1 >> 4, c41 = (i1 & 15) << 2;
        v4f av0, av1, bv0, bv1;
        cld4_4(av0, av1, bv0, bv1,
               &Qt[(kc + r0) * 1024 + a0 + c40],
               &Qt[(kc + r1) * 1024 + a0 + c41],
               &Qt[(kc + r0) * 1024 + b0 + c40],
               &Qt[(kc + r1) * 1024 + b0 + c41]);
        *(v4f*)&sm->gg.As[r0][c40] = av0;
        *(v4f*)&sm->gg.As[r1][c41] = av1;
        *(v4f*)&sm->gg.Bs[r0][c40] = bv0;
        *(v4f*)&sm->gg.Bs[r1][c41] = bv1;
        __syncthreads();
        for (int k = 0; k < 32; ++k) {
            float4 av = *(const float4*)&sm->gg.As[k][ty * 4];
            float4 bv = *(const float4*)&sm->gg.Bs[k][tx * 4];
            float a[4] = {av.x, av.y, av.z, av.w};
            float b[4] = {bv.x, bv.y, bv.z, bv.w};
            #pragma unroll
            for (int i = 0; i < 4; ++i)
                #pragma unroll
                for (int j = 0; j < 4; ++j) acc[i][j] += a[i] * b[j];
        }
        __syncthreads();
    }
    float rsum[4] = {0.f, 0.f, 0.f, 0.f};
    for (int i = 0; i < 4; ++i) {
        int aa = a0 + ty * 4 + i;
        float g[4];
        #pragma unroll
        for (int j = 0; j < 4; ++j) g[j] = 8.f * acc[i][j];
        float* gp = &G[aa * 1024 + b0 + tx * 4];
        ast2(gp, g[0], g[1]);
        ast2(gp + 2, g[2], g[3]);
        int bb = b0 + tx * 4;
        #pragma unroll
        for (int j = 0; j < 4; ++j) rsum[i] += (aa == bb + j) ? 0.f : fabsf(g[j]);
    }
    for (int i = 0; i < 4; ++i) sm->gg.Rs[ty * 4 + i][tx] = rsum[i];
    __syncthreads();
    if (tid < 64) {
        float s = 0.f;
        for (int x = 0; x < 16; ++x) s += sm->gg.Rs[tid][x];
        ast(&Rpart[(a0 + tid) * 16 + bx], s);
    }
}

// Ri[1024] into sm->gy.Ri; returns rth/delta (all threads)
__device__ __forceinline__ void dev_ri(Smem* sm, const float* Rpart,
                                       float* rth, float* delta) {
    int tid = threadIdx.x;
    float mn = 3.4e38f;
    for (int ee = 0; ee < 4; ee += 2) {
        int e0 = tid + ee * 256, e1 = e0 + 256;
        v4f t0, t1, t2, t3, u0, u1, u2, u3;
        cld4_8(t0, t1, t2, t3, u0, u1, u2, u3,
               &Rpart[e0 * 16], &Rpart[e0 * 16 + 4],
               &Rpart[e0 * 16 + 8], &Rpart[e0 * 16 + 12],
               &Rpart[e1 * 16], &Rpart[e1 * 16 + 4],
               &Rpart[e1 * 16 + 8], &Rpart[e1 * 16 + 12]);
        float s0 = 0.f;
        s0 += t0.x; s0 += t0.y; s0 += t0.z; s0 += t0.w;
        s0 += t1.x; s0 += t1.y; s0 += t1.z; s0 += t1.w;
        s0 += t2.x; s0 += t2.y; s0 += t2.z; s0 += t2.w;
        s0 += t3.x; s0 += t3.y; s0 += t3.z; s0 += t3.w;
        float s1 = 0.f;
        s1 += u0.x; s1 += u0.y; s1 += u0.z; s1 += u0.w;
        s1 += u1.x; s1 += u1.y; s1 += u1.z; s1 += u1.w;
        s1 += u2.x; s1 += u2.y; s1 += u2.z; s1 += u2.w;
        s1 += u3.x; s1 += u3.y; s1 += u3.z; s1 += u3.w;
        sm->gy.Ri[e0] = s0;
        sm->gy.Ri[e1] = s1;
        mn = fminf(mn, s0);
        mn = fminf(mn, s1);
    }
    sm->gy.red[tid] = mn;
    __syncthreads();
    for (int w = 128; w > 0; w >>= 1) {
        if (tid < w) sm->gy.red[tid] = fminf(sm->gy.red[tid], sm->gy.red[tid + w]);
        __syncthreads();
    }
    float r = sm->gy.red[0];
    *rth = r;
    *delta = r / 1023.f;
}

// Yslab[kz] = Qt * G' over K-chunk kz (256 wide); mask fused; Ri from LDS.
__device__ __forceinline__ void dev_gemmY(Smem* sm, const float* Qt, const float* G,
                                          float rth, float delta, float* Yslab, int bid) {
    int tid = threadIdx.x;
    int j0 = (bid & 15) * 64;
    int m0 = ((bid >> 4) & 3) * 32;
    int kz = bid >> 6;
    int kc0 = kz * 256;
    int tx = tid & 15, ty = tid >> 4;
    float acc[2][4] = {};
    for (int kc = kc0; kc < kc0 + 256; kc += 32) {
        int m = tid >> 3, k4 = (tid & 7) << 2;
        int iG0 = tid, iG1 = tid + 256;
        int rg0 = iG0 >> 4, cg0 = (iG0 & 15) << 2;
        int rg1 = iG1 >> 4, cg1 = (iG1 & 15) << 2;
        v4f q, g0, g1;
        cld4_3(q, g0, g1,
               &Qt[(m0 + m) * 1024 + kc + k4],
               &G[(kc + rg0) * 1024 + j0 + cg0],
               &G[(kc + rg1) * 1024 + j0 + cg1]);
        sm->gy.As[k4][m] = q.x;
        sm->gy.As[k4 + 1][m] = q.y;
        sm->gy.As[k4 + 2][m] = q.z;
        sm->gy.As[k4 + 3][m] = q.w;
        {
            int a = kc + rg0;
            float ria = sm->gy.Ri[a];
            #pragma unroll
            for (int u = 0; u < 4; ++u) {
                int b = j0 + cg0 + u;
                float g = g0[u];
                float sg = delta * ((g > 0.f) ? 1.f : ((g < 0.f) ? -1.f : 0.f));
                float ga = (ria > rth) ? sg : g;
                float gb = (sm->gy.Ri[b] > rth) ? sg : g;
                sm->gy.Bs[rg0][cg0 + u] = (a == b) ? g : 0.5f * (ga + gb);
            }
        }
        {
            int a = kc + rg1;
            float ria = sm->gy.Ri[a];
            #pragma unroll
            for (int u = 0; u < 4; ++u) {
                int b = j0 + cg1 + u;
                float g = g1[u];
                float sg = delta * ((g > 0.f) ? 1.f : ((g < 0.f) ? -1.f : 0.f));
                float ga = (ria > rth) ? sg : g;
                float gb = (sm->gy.Ri[b] > rth) ? sg : g;
                sm->gy.Bs[rg1][cg1 + u] = (a == b) ? g : 0.5f * (ga + gb);
            }
        }
        __syncthreads();
        for (int k = 0; k < 32; ++k) {
            float a0v = sm->gy.As[k][ty * 2], a1v = sm->gy.As[k][ty * 2 + 1];
            float4 bv = *(const float4*)&sm->gy.Bs[k][tx * 4];
            acc[0][0] += a0v * bv.x; acc[0][1] += a0v * bv.y;
            acc[0][2] += a0v * bv.z; acc[0][3] += a0v * bv.w;
            acc[1][0] += a1v * bv.x; acc[1][1] += a1v * bv.y;
            acc[1][2] += a1v * bv.z; acc[1][3] += a1v * bv.w;
        }
        __syncthreads();
    }
    float* outp = &Yslab[kz * 131072];
    for (int i = 0; i < 2; ++i) {
        float* op = &outp[(m0 + ty * 2 + i) * 1024 + j0 + tx * 4];
        ast2(op, acc[i][0], acc[i][1]);
        ast2(op + 2, acc[i][2], acc[i][3]);
    }
}

// trB partial: S-tile = (Qt^T Qt)[64x64] in regs; s += sum G'(G_old)⊙S ; atomicAdd
__device__ __forceinline__ void dev_trB(Smem* sm, const float* Qt, const float* G,
                                        const float* Rpart, float* accb, int bid) {
    int tid = threadIdx.x;
    float rth, delta;
    dev_ri(sm, Rpart, &rth, &delta);
    __syncthreads();
    int tx = tid & 15, ty = tid >> 4;
    int a0 = (bid >> 4) * 64, b0 = (bid & 15) * 64;
    float acc[4][4] = {};
    for (int kc = 0; kc < 128; kc += 32) {
        int i0 = tid, i1 = tid + 256;
        int r0 = i0 >> 4, c40 = (i0 & 15) << 2;
        int r1 = i1 >> 4, c41 = (i1 & 15) << 2;
        v4f av0, av1, bv0, bv1;
        cld4_4(av0, av1, bv0, bv1,
               &Qt[(kc + r0) * 1024 + a0 + c40],
               &Qt[(kc + r1) * 1024 + a0 + c41],
               &Qt[(kc + r0) * 1024 + b0 + c40],
               &Qt[(kc + r1) * 1024 + b0 + c41]);
        *(v4f*)&sm->syrk.As[r0][c40] = av0;
        *(v4f*)&sm->syrk.As[r1][c41] = av1;
        *(v4f*)&sm->syrk.Bs[r0][c40] = bv0;
        *(v4f*)&sm->syrk.Bs[r1][c41] = bv1;
        __syncthreads();
        for (int k = 0; k < 32; ++k) {
            float4 av = *(const float4*)&sm->syrk.As[k][ty * 4];
            float4 bv = *(const float4*)&sm->syrk.Bs[k][tx * 4];
            float a[4] = {av.x, av.y, av.z, av.w};
            float b[4] = {bv.x, bv.y, bv.z, bv.w};
            #pragma unroll
            for (int i = 0; i < 4; ++i)
                #pragma unroll
                for (int j = 0; j < 4; ++j) acc[i][j] += a[i] * b[j];
        }
        __syncthreads();
    }
    // re-derive Ri for the rows/cols we need (gy.Ri was clobbered by staging)
    float rib[4];
    for (int j = 0; j < 4; ++j) {
        int bb = b0 + tx * 4 + j;
        v4f t0, t1, t2, t3;
        cld4_4(t0, t1, t2, t3, &Rpart[bb * 16], &Rpart[bb * 16 + 4],
               &Rpart[bb * 16 + 8], &Rpart[bb * 16 + 12]);
        float s = 0.f;
        s += t0.x; s += t0.y; s += t0.z; s += t0.w;
        s += t1.x; s += t1.y; s += t1.z; s += t1.w;
        s += t2.x; s += t2.y; s += t2.z; s += t2.w;
        s += t3.x; s += t3.y; s += t3.z; s += t3.w;
        rib[j] = s;
    }
    float s = 0.f;
    for (int i = 0; i < 4; ++i) {
        int aa = a0 + ty * 4 + i;
        v4f t0, t1, t2, t3;
        cld4_4(t0, t1, t2, t3, &Rpart[aa * 16], &Rpart[aa * 16 + 4],
               &Rpart[aa * 16 + 8], &Rpart[aa * 16 + 12]);
        float ria = 0.f;
        ria += t0.x; ria += t0.y; ria += t0.z; ria += t0.w;
        ria += t1.x; ria += t1.y; ria += t1.z; ria += t1.w;
        ria += t2.x; ria += t2.y; ria += t2.z; ria += t2.w;
        ria += t3.x; ria += t3.y; ria += t3.z; ria += t3.w;
        float g0, g1, g2, g3;
        const float* gp = &G[aa * 1024 + b0 + tx * 4];
        cld1_4(g0, g1, g2, g3, gp, gp + 1, gp + 2, gp + 3);
        float gv[4] = {g0, g1, g2, g3};
        for (int j = 0; j < 4; ++j) {
            int bb = b0 + tx * 4 + j;
            float g = gv[j];
            float sg = delta * ((g > 0.f) ? 1.f : ((g < 0.f) ? -1.f : 0.f));
            float ga = (ria > rth) ? sg : g;
            float gb = (rib[j] > rth) ? sg : g;
            float gp2 = (aa == bb) ? g : 0.5f * (ga + gb);
            s += gp2 * acc[i][j];
        }
    }
    __syncthreads();
    sm->red[tid] = s;
    __syncthreads();
    for (int w = 128; w > 0; w >>= 1) {
        if (tid < w) sm->red[tid] += sm->red[tid + w];
        __syncthreads();
    }
    if (tid == 0) atomicAdd(&accb[2], sm->red[0]);
}

__global__ __launch_bounds__(256) void mega(const float* __restrict__ t1,
                                            const float* __restrict__ t2,
                                            const float* __restrict__ params,
                                            const float* __restrict__ tmin,
                                            const float* __restrict__ tmax,
                                            const float* __restrict__ beta,
                                            const float* __restrict__ R,
                                            float* ws, float* out) {
    float* G     = ws + OFF_G;
    float* Qt    = ws + OFF_QT;
    float* Yslab = ws + OFF_YS;
    float* Cslab = ws + OFF_CS;
    float* Lt    = ws + OFF_LT;
    float* Rpart = ws + OFF_RP;
    float* accb  = ws + OFF_ACC;
    unsigned* bb = (unsigned*)(ws + OFF_BAR);
    __shared__ Smem sm;
    int bid = blockIdx.x;
    unsigned phA = 0, phB = 0, phC = 0, phD = 0, phE = 0;

    if (bid < 32) dev_syrk(&sm, R, 1, R, 1, Cslab, bid);
    else if (bid < 250) dev_match(&sm, t1, t2, accb, bid - 32);
    else if (bid == 250) dev_range(&sm, params, tmin, tmax, accb);
    else if (bid < 255) dev_sumsq(&sm, R, accb, bid - 251);
    ++phC;
    if (bid < 32) bar_arrive(bb, BAR_C + (bid >> 2));
    if (bid == 0) { bar_wait(bb, BAR_C, 8, phC * 4); dev_chol(&sm, Cslab, Lt); }
    ++phD;
    if (bid == 0) bar_arrive(bb, BAR_D);
    if (bid < 32) { bar_wait(bb, BAR_D, 1, phD); dev_trsm(&sm, Lt, R, 1, Qt, bid); }
    ++phE;
    if (bid < 32) bar_arrive(bb, BAR_E + (bid >> 2));
    bar_wait(bb, BAR_E, 8, phE * 4);

    for (int it = 0; it < 50; ++it) {
        dev_gemmG(&sm, Qt, G, Rpart, bid);
        ++phA;
        bar_arrive(bb, BAR_A + (bid >> 3));
        bar_wait(bb, BAR_A, 32, phA * 8);
        {
            float rth, delta;
            dev_ri(&sm, Rpart, &rth, &delta);
            dev_gemmY(&sm, Qt, G, rth, delta, Yslab, bid);
        }
        ++phB;
        bar_arrive(bb, BAR_B + (bid >> 3));
        if (bid < 32) {
            bar_wait(bb, BAR_B, 32, phB * 8);
            dev_syrk(&sm, Yslab, 4, Yslab, 4, Cslab, bid);
        }
        ++phC;
        if (bid < 32) bar_arrive(bb, BAR_C + (bid >> 2));
        if (bid == 0) { bar_wait(bb, BAR_C, 8, phC * 4); dev_chol(&sm, Cslab, Lt); }
        ++phD;
        if (bid == 0) bar_arrive(bb, BAR_D);
        if (bid < 32) { bar_wait(bb, BAR_D, 1, phD); dev_trsm(&sm, Lt, Yslab, 4, Qt, bid); }
        ++phE;
        if (bid < 32) bar_arrive(bb, BAR_E + (bid >> 2));
        bar_wait(bb, BAR_E, 8, phE * 4);
    }

    dev_trB(&sm, Qt, G, Rpart, accb, bid);
    ++phA;
    bar_arrive(bb, BAR_A + (bid >> 3));
    if (bid == 0) {
        bar_wait(bb, BAR_A, 32, phA * 8);
        if (threadIdx.x == 0)
            out[0] = ald(&accb[0]) / 4194304.f + beta[0] * (ald(&accb[1]) / 2176.f)
                   + (ald(&accb[2]) + ald(&accb[3])) / 131072.f;
    }
}

extern "C" void kernel_launch(void* const* d_in, const int* in_sizes, int n_in,
                              void* d_out, int out_size, void* d_ws, size_t ws_size,
                              hipStream_t stream) {
    const float* t1 = (const float*)d_in[0];
    const float* t2 = (const float*)d_in[1];
    const float* params = (const float*)d_in[2];
    const float* tmin = (const float*)d_in[3];
    const float* tmax = (const float*)d_in[4];
    const float* beta = (const float*)d_in[5];
    const float* R = (const float*)d_in[6];
    float* ws = (float*)d_ws;
    float* out = (float*)d_out;

    hipMemsetAsync(ws + OFF_ACC, 0, 5312, stream);
    mega<<<NBLK, 256, 0, stream>>>(t1, t2, params, tmin, tmax, beta, R, ws, out);
}

// Round 8
// 7555.955 us; speedup vs baseline: 2.2722x; 1.1128x over previous
//
#include <hip/hip_runtime.h>

#define NBLK 256

// workspace layout (floats)
#define OFF_G    0            // 1024*1024
#define OFF_QT   1048576      // 128*1024
#define OFF_Y    1179648      // 128*1024 (atomic-accumulated)
#define OFF_C    1703936      // 128*128 (atomic-accumulated)
#define OFF_RP   1851392      // Rpart[1024][16]
#define OFF_ACC  1867776      // 4 floats
#define OFF_BAR  1867792      // 144 counter lines (stride 16 u32 = 64B)

#define BAR_A 0    // 64 lines, 256 arrive / 256 wait
#define BAR_B 64   // 64 lines, 256 arrive / 32 wait
#define BAR_C 128  // 8 lines, 32 arrive / 32 wait
#define BAR_E 136  // 8 lines, 32 arrive / 256 wait

typedef float v4f __attribute__((ext_vector_type(4)));

// ---- batched agent-coherent loads (sc1), wait included ----
__device__ __forceinline__ void cld4_4(v4f& a, v4f& b, v4f& c, v4f& d,
                                       const float* pa, const float* pb,
                                       const float* pc, const float* pd) {
    asm volatile("global_load_dwordx4 %0, %4, off sc1\n\t"
                 "global_load_dwordx4 %1, %5, off sc1\n\t"
                 "global_load_dwordx4 %2, %6, off sc1\n\t"
                 "global_load_dwordx4 %3, %7, off sc1\n\t"
                 "s_waitcnt vmcnt(0)"
                 : "=&v"(a), "=&v"(b), "=&v"(c), "=&v"(d)
                 : "v"(pa), "v"(pb), "v"(pc), "v"(pd) : "memory");
}
__device__ __forceinline__ void cld4_8(v4f& a, v4f& b, v4f& c, v4f& d,
                                       v4f& e, v4f& f, v4f& g, v4f& h,
                                       const float* pa, const float* pb,
                                       const float* pc, const float* pd,
                                       const float* pe, const float* pf,
                                       const float* pg, const float* ph) {
    asm volatile("global_load_dwordx4 %0, %8, off sc1\n\t"
                 "global_load_dwordx4 %1, %9, off sc1\n\t"
                 "global_load_dwordx4 %2, %10, off sc1\n\t"
                 "global_load_dwordx4 %3, %11, off sc1\n\t"
                 "global_load_dwordx4 %4, %12, off sc1\n\t"
                 "global_load_dwordx4 %5, %13, off sc1\n\t"
                 "global_load_dwordx4 %6, %14, off sc1\n\t"
                 "global_load_dwordx4 %7, %15, off sc1\n\t"
                 "s_waitcnt vmcnt(0)"
                 : "=&v"(a), "=&v"(b), "=&v"(c), "=&v"(d),
                   "=&v"(e), "=&v"(f), "=&v"(g), "=&v"(h)
                 : "v"(pa), "v"(pb), "v"(pc), "v"(pd),
                   "v"(pe), "v"(pf), "v"(pg), "v"(ph) : "memory");
}
__device__ __forceinline__ void cld1_4(float& a, float& b, float& c, float& d,
                                       const float* pa, const float* pb,
                                       const float* pc, const float* pd) {
    asm volatile("global_load_dword %0, %4, off sc1\n\t"
                 "global_load_dword %1, %5, off sc1\n\t"
                 "global_load_dword %2, %6, off sc1\n\t"
                 "global_load_dword %3, %7, off sc1\n\t"
                 "s_waitcnt vmcnt(0)"
                 : "=&v"(a), "=&v"(b), "=&v"(c), "=&v"(d)
                 : "v"(pa), "v"(pb), "v"(pc), "v"(pd) : "memory");
}
__device__ __forceinline__ void cld1_8(float& a, float& b, float& c, float& d,
                                       float& e, float& f, float& g, float& h,
                                       const float* pa, const float* pb,
                                       const float* pc, const float* pd,
                                       const float* pe, const float* pf,
                                       const float* pg, const float* ph) {
    asm volatile("global_load_dword %0, %8, off sc1\n\t"
                 "global_load_dword %1, %9, off sc1\n\t"
                 "global_load_dword %2, %10, off sc1\n\t"
                 "global_load_dword %3, %11, off sc1\n\t"
                 "global_load_dword %4, %12, off sc1\n\t"
                 "global_load_dword %5, %13, off sc1\n\t"
                 "global_load_dword %6, %14, off sc1\n\t"
                 "global_load_dword %7, %15, off sc1\n\t"
                 "s_waitcnt vmcnt(0)"
                 : "=&v"(a), "=&v"(b), "=&v"(c), "=&v"(d),
                   "=&v"(e), "=&v"(f), "=&v"(g), "=&v"(h)
                 : "v"(pa), "v"(pb), "v"(pc), "v"(pd),
                   "v"(pe), "v"(pf), "v"(pg), "v"(ph) : "memory");
}
// ---- issue-only variants + explicit waits (prefetch pipelining) ----
__device__ __forceinline__ void iss4(v4f& a, v4f& b, v4f& c, v4f& d,
                                     const float* pa, const float* pb,
                                     const float* pc, const float* pd) {
    asm volatile("global_load_dwordx4 %0, %4, off sc1\n\t"
                 "global_load_dwordx4 %1, %5, off sc1\n\t"
                 "global_load_dwordx4 %2, %6, off sc1\n\t"
                 "global_load_dwordx4 %3, %7, off sc1"
                 : "=&v"(a), "=&v"(b), "=&v"(c), "=&v"(d)
                 : "v"(pa), "v"(pb), "v"(pc), "v"(pd) : "memory");
}
__device__ __forceinline__ void wt4(v4f& a, v4f& b, v4f& c, v4f& d) {
    asm volatile("s_waitcnt vmcnt(0)"
                 : "+v"(a), "+v"(b), "+v"(c), "+v"(d) :: "memory");
}
__device__ __forceinline__ void iss3(v4f& a, v4f& b, v4f& c,
                                     const float* pa, const float* pb,
                                     const float* pc) {
    asm volatile("global_load_dwordx4 %0, %3, off sc1\n\t"
                 "global_load_dwordx4 %1, %4, off sc1\n\t"
                 "global_load_dwordx4 %2, %5, off sc1"
                 : "=&v"(a), "=&v"(b), "=&v"(c)
                 : "v"(pa), "v"(pb), "v"(pc) : "memory");
}
__device__ __forceinline__ void wt3(v4f& a, v4f& b, v4f& c) {
    asm volatile("s_waitcnt vmcnt(0)" : "+v"(a), "+v"(b), "+v"(c) :: "memory");
}

// ---- coherent scalar/pair stores + loads ----
__device__ __forceinline__ void ast2(float* p, float a, float b) {
    union { unsigned long long u; float f[2]; } c; c.f[0] = a; c.f[1] = b;
    __hip_atomic_store((unsigned long long*)p, c.u,
                       __ATOMIC_RELAXED, __HIP_MEMORY_SCOPE_AGENT);
}
__device__ __forceinline__ float ald(const float* p) {
    return __hip_atomic_load(p, __ATOMIC_RELAXED, __HIP_MEMORY_SCOPE_AGENT);
}
__device__ __forceinline__ void ast(float* p, float x) {
    __hip_atomic_store(p, x, __ATOMIC_RELAXED, __HIP_MEMORY_SCOPE_AGENT);
}

__device__ __forceinline__ void bar_arrive(unsigned* bb, int line) {
    __syncthreads();
    if (threadIdx.x == 0)
        __hip_atomic_fetch_add(bb + line * 16, 1u,
                               __ATOMIC_RELAXED, __HIP_MEMORY_SCOPE_AGENT);
}
__device__ __forceinline__ void bar_wait(unsigned* bb, int wbase, int nlines,
                                         unsigned tgt) {
    if ((int)threadIdx.x < nlines) {
        while (__hip_atomic_load(bb + (wbase + threadIdx.x) * 16,
                                 __ATOMIC_RELAXED, __HIP_MEMORY_SCOPE_AGENT) < tgt)
            __builtin_amdgcn_s_sleep(1);
    }
    __builtin_amdgcn_s_waitcnt(0);
    __syncthreads();
}

union Smem {
    struct { float As[32][68]; float Bs[32][68]; float Rs[64][16]; } gg;   // gemmG + syrk
    struct { float Cs[128][129]; float inv_d[16]; float irs[128];
             float Xs[16][32]; } chol;                                     // 68672 B
    struct { float Ri[1024]; float red[256]; float As[32][33]; float Bs[32][68]; } gy;
    struct { float As[32][68]; float Bs[32][68]; float red[256]; } tb;
    float red[256];
};

__device__ __forceinline__ void dev_match(Smem* sm, const float* t1, const float* t2,
                                          float* accb, int w) {
    int tid = threadIdx.x;
    const float4* a = (const float4*)t1;
    const float4* b = (const float4*)t2;
    float s = 0.f;
    for (int i = w * 256 + tid; i < 1048576; i += 218 * 256) {
        float4 x = a[i], y = b[i];
        float d0 = x.x - y.x, d1 = x.y - y.y, d2 = x.z - y.z, d3 = x.w - y.w;
        s += d0 * d0 + d1 * d1 + d2 * d2 + d3 * d3;
    }
    sm->red[tid] = s; __syncthreads();
    for (int w2 = 128; w2 > 0; w2 >>= 1) {
        if (tid < w2) sm->red[tid] += sm->red[tid + w2];
        __syncthreads();
    }
    if (tid == 0) atomicAdd(&accb[0], sm->red[0]);
    __syncthreads();
}

__device__ __forceinline__ void dev_range(Smem* sm, const float* params, const float* tmin,
                                          const float* tmax, float* accb) {
    int tid = threadIdx.x;
    float a = tmin[0], b = tmax[0];
    const float d = 0.01f;
    float s = 0.f;
    for (int i = tid; i < 128 * 17; i += 256) {
        float p = params[i];
        float r1 = (p - a - d) / (-d);
        float r2 = (p - b + d) / d;
        s += fmaxf(fmaxf(r1, r2), 0.f);
    }
    sm->red[tid] = s; __syncthreads();
    for (int w = 128; w > 0; w >>= 1) {
        if (tid < w) sm->red[tid] += sm->red[tid + w];
        __syncthreads();
    }
    if (tid == 0) atomicAdd(&accb[1], sm->red[0]);
    __syncthreads();
}

__device__ __forceinline__ void dev_sumsq(Smem* sm, const float* X, float* accb, int w) {
    int tid = threadIdx.x;
    float s = 0.f;
    for (int i = w * 256 + tid; i < 131072; i += 1024) { float v = X[i]; s += v * v; }
    sm->red[tid] = s; __syncthreads();
    for (int w2 = 128; w2 > 0; w2 >>= 1) {
        if (tid < w2) sm->red[tid] += sm->red[tid + w2];
        __syncthreads();
    }
    if (tid == 0) atomicAdd(&accb[3], sm->red[0]);
    __syncthreads();
}

// C += A-tile(64 rows p0) x B-tile(64 rows q0) over K-chunk z of 128 (atomicAdd).
__device__ __forceinline__ void dev_syrk(Smem* sm, const float* A, const float* B,
                                         float* C, int bid) {
    int tid = threadIdx.x;
    int q0 = (bid & 1) * 64, p0 = ((bid >> 1) & 1) * 64, z = bid >> 2;
    int kc0 = z * 128;
    int p = tid & 63, kq = tid >> 6;
    int kg = kq * 8;
    int tx = tid & 15, ty = tid >> 4;
    float acc[4][4] = {};
    v4f a0v, a1v, b0v, b1v;
    {
        const float* pa = &A[(p0 + p) * 1024 + kc0 + kg];
        const float* pb = &B[(q0 + p) * 1024 + kc0 + kg];
        iss4(a0v, a1v, b0v, b1v, pa, pa + 4, pb, pb + 4);
    }
    for (int ck = 0; ck < 4; ++ck) {
        wt4(a0v, a1v, b0v, b1v);
        __syncthreads();
        sm->gg.As[kg + 0][p] = a0v.x; sm->gg.As[kg + 1][p] = a0v.y;
        sm->gg.As[kg + 2][p] = a0v.z; sm->gg.As[kg + 3][p] = a0v.w;
        sm->gg.As[kg + 4][p] = a1v.x; sm->gg.As[kg + 5][p] = a1v.y;
        sm->gg.As[kg + 6][p] = a1v.z; sm->gg.As[kg + 7][p] = a1v.w;
        sm->gg.Bs[kg + 0][p] = b0v.x; sm->gg.Bs[kg + 1][p] = b0v.y;
        sm->gg.Bs[kg + 2][p] = b0v.z; sm->gg.Bs[kg + 3][p] = b0v.w;
        sm->gg.Bs[kg + 4][p] = b1v.x; sm->gg.Bs[kg + 5][p] = b1v.y;
        sm->gg.Bs[kg + 6][p] = b1v.z; sm->gg.Bs[kg + 7][p] = b1v.w;
        __syncthreads();
        if (ck < 3) {
            const float* pa = &A[(p0 + p) * 1024 + kc0 + (ck + 1) * 32 + kg];
            const float* pb = &B[(q0 + p) * 1024 + kc0 + (ck + 1) * 32 + kg];
            iss4(a0v, a1v, b0v, b1v, pa, pa + 4, pb, pb + 4);
        }
        for (int k = 0; k < 32; ++k) {
            float4 av = *(const float4*)&sm->gg.As[k][ty * 4];
            float4 bv = *(const float4*)&sm->gg.Bs[k][tx * 4];
            float a[4] = {av.x, av.y, av.z, av.w};
            float b[4] = {bv.x, bv.y, bv.z, bv.w};
            #pragma unroll
            for (int i = 0; i < 4; ++i)
                #pragma unroll
                for (int j = 0; j < 4; ++j) acc[i][j] += a[i] * b[j];
        }
        __syncthreads();
    }
    for (int i = 0; i < 4; ++i)
        for (int j = 0; j < 4; ++j)
            atomicAdd(&C[(p0 + ty * 4 + i) * 128 + q0 + tx * 4 + j], acc[i][j]);
}

// Fused: redundant Cholesky of C (each block) + forward solve for 32 columns.
// L kept in factored-Cs form; per-column scaling via irs[].
__device__ __forceinline__ void dev_cholTrsm(Smem* sm, const float* C, const float* RHS,
                                             float* Qt, int bid) {
    int tid = threadIdx.x;
    // stage C (64 floats/thread = 16 v4f in 2 batches)
    {
        const float* base = C + tid * 64;
        v4f z0, z1, z2, z3, z4, z5, z6, z7;
        cld4_8(z0, z1, z2, z3, z4, z5, z6, z7,
               base, base + 4, base + 8, base + 12,
               base + 16, base + 20, base + 24, base + 28);
        int r = tid >> 1, c0 = (tid & 1) * 64;
        *(v4f*)&sm->chol.Cs[r][c0]      = z0; *(v4f*)&sm->chol.Cs[r][c0 + 4]  = z1;
        *(v4f*)&sm->chol.Cs[r][c0 + 8]  = z2; *(v4f*)&sm->chol.Cs[r][c0 + 12] = z3;
        *(v4f*)&sm->chol.Cs[r][c0 + 16] = z4; *(v4f*)&sm->chol.Cs[r][c0 + 20] = z5;
        *(v4f*)&sm->chol.Cs[r][c0 + 24] = z6; *(v4f*)&sm->chol.Cs[r][c0 + 28] = z7;
        cld4_8(z0, z1, z2, z3, z4, z5, z6, z7,
               base + 32, base + 36, base + 40, base + 44,
               base + 48, base + 52, base + 56, base + 60);
        *(v4f*)&sm->chol.Cs[r][c0 + 32] = z0; *(v4f*)&sm->chol.Cs[r][c0 + 36] = z1;
        *(v4f*)&sm->chol.Cs[r][c0 + 40] = z2; *(v4f*)&sm->chol.Cs[r][c0 + 44] = z3;
        *(v4f*)&sm->chol.Cs[r][c0 + 48] = z4; *(v4f*)&sm->chol.Cs[r][c0 + 52] = z5;
        *(v4f*)&sm->chol.Cs[r][c0 + 56] = z6; *(v4f*)&sm->chol.Cs[r][c0 + 60] = z7;
    }
    __syncthreads();
    int lane = tid & 63;
    for (int kb = 0; kb < 8; ++kb) {
        int k0 = kb * 16;
        if (tid < 64) {
            float P0[16], P1[16], invs[16];
            #pragma unroll
            for (int u = 0; u < 16; ++u) {
                P0[u] = sm->chol.Cs[lane][k0 + u];
                P1[u] = sm->chol.Cs[lane + 64][k0 + u];
            }
            #pragma unroll
            for (int kk = 0; kk < 16; ++kk) {
                int k = k0 + kk;
                int src = k & 63;
                bool hi = (k >= 64);
                float pr[16];
                #pragma unroll
                for (int u = 0; u < 16; ++u)
                    if (u >= kk) pr[u] = __shfl(hi ? P1[u] : P0[u], src);
                float inv = 1.0f / pr[kk];
                invs[kk] = inv;
                float f0 = (lane > k) ? P0[kk] * inv : 0.f;
                float f1 = ((lane + 64) > k) ? P1[kk] * inv : 0.f;
                #pragma unroll
                for (int u = kk + 1; u < 16; ++u) {
                    P0[u] -= f0 * pr[u];
                    P1[u] -= f1 * pr[u];
                }
            }
            #pragma unroll
            for (int u = 0; u < 16; ++u) {
                sm->chol.Cs[lane][k0 + u] = P0[u];
                sm->chol.Cs[lane + 64][k0 + u] = P1[u];
            }
            if (lane == 0) {
                #pragma unroll
                for (int kk = 0; kk < 16; ++kk) sm->chol.inv_d[kk] = invs[kk];
            }
        }
        __syncthreads();
        int base = k0 + 16;
        if (base < 128) {
            int h = tid >> 6, c = tid & 63;
            int j1 = base + c;
            int j2 = base + c + 64;
            bool has1 = (j1 < 128), has2 = (j2 < 128);
            float w1[16], w2[16];
            if (has1) {
                #pragma unroll
                for (int u = 0; u < 16; ++u) w1[u] = sm->chol.Cs[j1][k0 + u] * sm->chol.inv_d[u];
            }
            if (has2) {
                #pragma unroll
                for (int u = 0; u < 16; ++u) w2[u] = sm->chol.Cs[j2][k0 + u] * sm->chol.inv_d[u];
            }
            int rlo = h * 32;
            int istart = rlo > base ? rlo : base;
            for (int i = istart; i < rlo + 32; ++i) {
                float v[16];
                #pragma unroll
                for (int u = 0; u < 16; ++u) v[u] = sm->chol.Cs[i][k0 + u];
                float a1 = 0.f, a2 = 0.f;
                #pragma unroll
                for (int u = 0; u < 16; ++u) { a1 += v[u] * w1[u]; a2 += v[u] * w2[u]; }
                if (has1) sm->chol.Cs[i][j1] -= a1;
                if (has2) sm->chol.Cs[i][j2] -= a2;
            }
        }
        __syncthreads();
    }
    if (tid < 128) sm->chol.irs[tid] = 1.0f / sqrtf(sm->chol.Cs[tid][tid]);
    // RHS: 16 rows per band, column per thread
    int c = tid & 31, h = tid >> 5;
    int j0 = bid * 32;
    float acc[16];
    {
        const float* p = &RHS[(h * 16) * 1024 + j0 + c];
        cld1_8(acc[0], acc[1], acc[2], acc[3], acc[4], acc[5], acc[6], acc[7],
               p, p + 1024, p + 2048, p + 3072, p + 4096, p + 5120, p + 6144, p + 7168);
        cld1_8(acc[8], acc[9], acc[10], acc[11], acc[12], acc[13], acc[14], acc[15],
               p + 8192, p + 9216, p + 10240, p + 11264,
               p + 12288, p + 13312, p + 14336, p + 15360);
    }
    __syncthreads();
    for (int pb = 0; pb < 8; ++pb) {
        int p0 = pb * 16;
        if (h == pb) {
            #pragma unroll
            for (int kk = 0; kk < 16; ++kk) {
                int k = p0 + kk;
                float irsk = sm->chol.irs[k];
                float x = acc[kk] * irsk;
                acc[kk] = x;
                sm->chol.Xs[kk][c] = x;
                float xs = x * irsk;
                #pragma unroll
                for (int r = kk + 1; r < 16; ++r)
                    acc[r] -= sm->chol.Cs[p0 + r][k] * xs;
            }
        }
        __syncthreads();
        if (h > pb) {
            int rb = h * 16;
            #pragma unroll
            for (int kk = 0; kk < 16; ++kk) {
                int k = p0 + kk;
                float xs = sm->chol.Xs[kk][c] * sm->chol.irs[k];
                #pragma unroll
                for (int r = 0; r < 16; ++r)
                    acc[r] -= sm->chol.Cs[rb + r][k] * xs;
            }
        }
        __syncthreads();
    }
    #pragma unroll
    for (int r = 0; r < 16; ++r)
        ast(&Qt[(h * 16 + r) * 1024 + j0 + c], acc[r]);
}

// G = 8*Qt^T Qt + per-block row abs-sum partials (Rpart[row][16]); prefetched.
__device__ __forceinline__ void dev_gemmG(Smem* sm, const float* Qt, float* G,
                                          float* Rpart, int bid) {
    int tid = threadIdx.x;
    int tx = tid & 15, ty = tid >> 4;
    int bx = bid & 15, by = bid >> 4;
    int a0 = by * 64, b0 = bx * 64;
    int r0 = tid >> 4, c4 = (tid & 15) << 2;
    int r1 = 16 + r0;
    float acc[4][4] = {};
    v4f av0, av1, bv0, bv1;
    iss4(av0, av1, bv0, bv1,
         &Qt[r0 * 1024 + a0 + c4], &Qt[r1 * 1024 + a0 + c4],
         &Qt[r0 * 1024 + b0 + c4], &Qt[r1 * 1024 + b0 + c4]);
    for (int kc = 0; kc < 128; kc += 32) {
        wt4(av0, av1, bv0, bv1);
        __syncthreads();
        *(v4f*)&sm->gg.As[r0][c4] = av0;
        *(v4f*)&sm->gg.As[r1][c4] = av1;
        *(v4f*)&sm->gg.Bs[r0][c4] = bv0;
        *(v4f*)&sm->gg.Bs[r1][c4] = bv1;
        __syncthreads();
        if (kc < 96) {
            int kn = kc + 32;
            iss4(av0, av1, bv0, bv1,
                 &Qt[(kn + r0) * 1024 + a0 + c4], &Qt[(kn + r1) * 1024 + a0 + c4],
                 &Qt[(kn + r0) * 1024 + b0 + c4], &Qt[(kn + r1) * 1024 + b0 + c4]);
        }
        for (int k = 0; k < 32; ++k) {
            float4 av = *(const float4*)&sm->gg.As[k][ty * 4];
            float4 bv = *(const float4*)&sm->gg.Bs[k][tx * 4];
            float a[4] = {av.x, av.y, av.z, av.w};
            float b[4] = {bv.x, bv.y, bv.z, bv.w};
            #pragma unroll
            for (int i = 0; i < 4; ++i)
                #pragma unroll
                for (int j = 0; j < 4; ++j) acc[i][j] += a[i] * b[j];
        }
        __syncthreads();
    }
    float rsum[4] = {0.f, 0.f, 0.f, 0.f};
    for (int i = 0; i < 4; ++i) {
        int aa = a0 + ty * 4 + i;
        float g[4];
        #pragma unroll
        for (int j = 0; j < 4; ++j) g[j] = 8.f * acc[i][j];
        float* gp = &G[aa * 1024 + b0 + tx * 4];
        ast2(gp, g[0], g[1]);
        ast2(gp + 2, g[2], g[3]);
        int bb = b0 + tx * 4;
        #pragma unroll
        for (int j = 0; j < 4; ++j) rsum[i] += (aa == bb + j) ? 0.f : fabsf(g[j]);
    }
    for (int i = 0; i < 4; ++i) sm->gg.Rs[ty * 4 + i][tx] = rsum[i];
    __syncthreads();
    if (tid < 64) {
        float s = 0.f;
        for (int x = 0; x < 16; ++x) s += sm->gg.Rs[tid][x];
        ast(&Rpart[(a0 + tid) * 16 + bx], s);
    }
}

// Ri[1024] into sm->gy.Ri; returns rth/delta (all threads)
__device__ __forceinline__ void dev_ri(Smem* sm, const float* Rpart,
                                       float* rth, float* delta) {
    int tid = threadIdx.x;
    float mn = 3.4e38f;
    for (int ee = 0; ee < 4; ee += 2) {
        int e0 = tid + ee * 256, e1 = e0 + 256;
        v4f t0, t1, t2, t3, u0, u1, u2, u3;
        cld4_8(t0, t1, t2, t3, u0, u1, u2, u3,
               &Rpart[e0 * 16], &Rpart[e0 * 16 + 4],
               &Rpart[e0 * 16 + 8], &Rpart[e0 * 16 + 12],
               &Rpart[e1 * 16], &Rpart[e1 * 16 + 4],
               &Rpart[e1 * 16 + 8], &Rpart[e1 * 16 + 12]);
        float s0 = 0.f;
        s0 += t0.x; s0 += t0.y; s0 += t0.z; s0 += t0.w;
        s0 += t1.x; s0 += t1.y; s0 += t1.z; s0 += t1.w;
        s0 += t2.x; s0 += t2.y; s0 += t2.z; s0 += t2.w;
        s0 += t3.x; s0 += t3.y; s0 += t3.z; s0 += t3.w;
        float s1 = 0.f;
        s1 += u0.x; s1 += u0.y; s1 += u0.z; s1 += u0.w;
        s1 += u1.x; s1 += u1.y; s1 += u1.z; s1 += u1.w;
        s1 += u2.x; s1 += u2.y; s1 += u2.z; s1 += u2.w;
        s1 += u3.x; s1 += u3.y; s1 += u3.z; s1 += u3.w;
        sm->gy.Ri[e0] = s0;
        sm->gy.Ri[e1] = s1;
        mn = fminf(mn, s0);
        mn = fminf(mn, s1);
    }
    sm->gy.red[tid] = mn;
    __syncthreads();
    for (int w = 128; w > 0; w >>= 1) {
        if (tid < w) sm->gy.red[tid] = fminf(sm->gy.red[tid], sm->gy.red[tid + w]);
        __syncthreads();
    }
    float r = sm->gy.red[0];
    *rth = r;
    *delta = r / 1023.f;
}

// Y += Qt * G' over K-chunk kz (256 wide, atomicAdd); mask fused; prefetched.
__device__ __forceinline__ void dev_gemmY(Smem* sm, const float* Qt, const float* G,
                                          float rth, float delta, float* Y, int bid) {
    int tid = threadIdx.x;
    int j0 = (bid & 15) * 64;
    int m0 = ((bid >> 4) & 3) * 32;
    int kz = bid >> 6;
    int kc0 = kz * 256;
    int tx = tid & 15, ty = tid >> 4;
    int m = tid >> 3, k4 = (tid & 7) << 2;
    int rg0 = tid >> 4, cg0 = (tid & 15) << 2, rg1 = 16 + rg0;
    float acc[2][4] = {};
    v4f q, g0, g1;
    iss3(q, g0, g1,
         &Qt[(m0 + m) * 1024 + kc0 + k4],
         &G[(kc0 + rg0) * 1024 + j0 + cg0],
         &G[(kc0 + rg1) * 1024 + j0 + cg0]);
    for (int kc = kc0; kc < kc0 + 256; kc += 32) {
        wt3(q, g0, g1);
        __syncthreads();
        sm->gy.As[k4][m] = q.x;
        sm->gy.As[k4 + 1][m] = q.y;
        sm->gy.As[k4 + 2][m] = q.z;
        sm->gy.As[k4 + 3][m] = q.w;
        {
            int a = kc + rg0;
            float ria = sm->gy.Ri[a];
            #pragma unroll
            for (int u = 0; u < 4; ++u) {
                int b = j0 + cg0 + u;
                float g = g0[u];
                float sg = delta * ((g > 0.f) ? 1.f : ((g < 0.f) ? -1.f : 0.f));
                float ga = (ria > rth) ? sg : g;
                float gb = (sm->gy.Ri[b] > rth) ? sg : g;
                sm->gy.Bs[rg0][cg0 + u] = (a == b) ? g : 0.5f * (ga + gb);
            }
        }
        {
            int a = kc + rg1;
            float ria = sm->gy.Ri[a];
            #pragma unroll
            for (int u = 0; u < 4; ++u) {
                int b = j0 + cg0 + u;
                float g = g1[u];
                float sg = delta * ((g > 0.f) ? 1.f : ((g < 0.f) ? -1.f : 0.f));
                float ga = (ria > rth) ? sg : g;
                float gb = (sm->gy.Ri[b] > rth) ? sg : g;
                sm->gy.Bs[rg1][cg0 + u] = (a == b) ? g : 0.5f * (ga + gb);
            }
        }
        __syncthreads();
        if (kc < kc0 + 224) {
            int kn = kc + 32;
            iss3(q, g0, g1,
                 &Qt[(m0 + m) * 1024 + kn + k4],
                 &G[(kn + rg0) * 1024 + j0 + cg0],
                 &G[(kn + rg1) * 1024 + j0 + cg0]);
        }
        for (int k = 0; k < 32; ++k) {
            float a0v = sm->gy.As[k][ty * 2], a1v = sm->gy.As[k][ty * 2 + 1];
            float4 bv = *(const float4*)&sm->gy.Bs[k][tx * 4];
            acc[0][0] += a0v * bv.x; acc[0][1] += a0v * bv.y;
            acc[0][2] += a0v * bv.z; acc[0][3] += a0v * bv.w;
            acc[1][0] += a1v * bv.x; acc[1][1] += a1v * bv.y;
            acc[1][2] += a1v * bv.z; acc[1][3] += a1v * bv.w;
        }
        __syncthreads();
    }
    for (int i = 0; i < 2; ++i)
        for (int j = 0; j < 4; ++j)
            atomicAdd(&Y[(m0 + ty * 2 + i) * 1024 + j0 + tx * 4 + j], acc[i][j]);
}

// trB partial: S-tile = (Qt^T Qt)[64x64]; s += sum G'(G_old)⊙S ; atomicAdd
__device__ __forceinline__ void dev_trB(Smem* sm, const float* Qt, const float* G,
                                        const float* Rpart, float* accb, int bid) {
    int tid = threadIdx.x;
    float rth, delta;
    dev_ri(sm, Rpart, &rth, &delta);
    __syncthreads();
    int tx = tid & 15, ty = tid >> 4;
    int a0 = (bid >> 4) * 64, b0 = (bid & 15) * 64;
    float acc[4][4] = {};
    for (int kc = 0; kc < 128; kc += 32) {
        int i0 = tid, i1 = tid + 256;
        int r0 = i0 >> 4, c40 = (i0 & 15) << 2;
        int r1 = i1 >> 4, c41 = (i1 & 15) << 2;
        v4f av0, av1, bv0, bv1;
        cld4_4(av0, av1, bv0, bv1,
               &Qt[(kc + r0) * 1024 + a0 + c40],
               &Qt[(kc + r1) * 1024 + a0 + c41],
               &Qt[(kc + r0) * 1024 + b0 + c40],
               &Qt[(kc + r1) * 1024 + b0 + c41]);
        __syncthreads();
        *(v4f*)&sm->tb.As[r0][c40] = av0;
        *(v4f*)&sm->tb.As[r1][c41] = av1;
        *(v4f*)&sm->tb.Bs[r0][c40] = bv0;
        *(v4f*)&sm->tb.Bs[r1][c41] = bv1;
        __syncthreads();
        for (int k = 0; k < 32; ++k) {
            float4 av = *(const float4*)&sm->tb.As[k][ty * 4];
            float4 bv = *(const float4*)&sm->tb.Bs[k][tx * 4];
            float a[4] = {av.x, av.y, av.z, av.w};
            float b[4] = {bv.x, bv.y, bv.z, bv.w};
            #pragma unroll
            for (int i = 0; i < 4; ++i)
                #pragma unroll
                for (int j = 0; j < 4; ++j) acc[i][j] += a[i] * b[j];
        }
        __syncthreads();
    }
    float rib[4];
    for (int j = 0; j < 4; ++j) {
        int bb = b0 + tx * 4 + j;
        v4f t0, t1, t2, t3;
        cld4_4(t0, t1, t2, t3, &Rpart[bb * 16], &Rpart[bb * 16 + 4],
               &Rpart[bb * 16 + 8], &Rpart[bb * 16 + 12]);
        float s = 0.f;
        s += t0.x; s += t0.y; s += t0.z; s += t0.w;
        s += t1.x; s += t1.y; s += t1.z; s += t1.w;
        s += t2.x; s += t2.y; s += t2.z; s += t2.w;
        s += t3.x; s += t3.y; s += t3.z; s += t3.w;
        rib[j] = s;
    }
    float s = 0.f;
    for (int i = 0; i < 4; ++i) {
        int aa = a0 + ty * 4 + i;
        v4f t0, t1, t2, t3;
        cld4_4(t0, t1, t2, t3, &Rpart[aa * 16], &Rpart[aa * 16 + 4],
               &Rpart[aa * 16 + 8], &Rpart[aa * 16 + 12]);
        float ria = 0.f;
        ria += t0.x; ria += t0.y; ria += t0.z; ria += t0.w;
        ria += t1.x; ria += t1.y; ria += t1.z; ria += t1.w;
        ria += t2.x; ria += t2.y; ria += t2.z; ria += t2.w;
        ria += t3.x; ria += t3.y; ria += t3.z; ria += t3.w;
        float g0, g1, g2, g3;
        const float* gp = &G[aa * 1024 + b0 + tx * 4];
        cld1_4(g0, g1, g2, g3, gp, gp + 1, gp + 2, gp + 3);
        float gv[4] = {g0, g1, g2, g3};
        for (int j = 0; j < 4; ++j) {
            int bb = b0 + tx * 4 + j;
            float g = gv[j];
            float sg = delta * ((g > 0.f) ? 1.f : ((g < 0.f) ? -1.f : 0.f));
            float ga = (ria > rth) ? sg : g;
            float gb = (rib[j] > rth) ? sg : g;
            float gp2 = (aa == bb) ? g : 0.5f * (ga + gb);
            s += gp2 * acc[i][j];
        }
    }
    __syncthreads();
    sm->tb.red[tid] = s;
    __syncthreads();
    for (int w = 128; w > 0; w >>= 1) {
        if (tid < w) sm->tb.red[tid] += sm->tb.red[tid + w];
        __syncthreads();
    }
    if (tid == 0) atomicAdd(&accb[2], sm->tb.red[0]);
}

__global__ __launch_bounds__(256) void mega(const float* __restrict__ t1,
                                            const float* __restrict__ t2,
                                            const float* __restrict__ params,
                                            const float* __restrict__ tmin,
                                            const float* __restrict__ tmax,
                                            const float* __restrict__ beta,
                                            const float* __restrict__ R,
                                            float* ws, float* out) {
    float* G     = ws + OFF_G;
    float* Qt    = ws + OFF_QT;
    float* Y     = ws + OFF_Y;
    float* C     = ws + OFF_C;
    float* Rpart = ws + OFF_RP;
    float* accb  = ws + OFF_ACC;
    unsigned* bb = (unsigned*)(ws + OFF_BAR);
    __shared__ Smem sm;
    int bid = blockIdx.x;
    int tid = threadIdx.x;
    unsigned phA = 0, phB = 0, phC = 0, phE = 0;

    // P0a: zero C (blocks 0-31); stats elsewhere
    if (bid < 32) {
        ast2(&C[bid * 512 + tid * 2], 0.f, 0.f);
    } else if (bid < 250) dev_match(&sm, t1, t2, accb, bid - 32);
    else if (bid == 250) dev_range(&sm, params, tmin, tmax, accb);
    else if (bid < 255) dev_sumsq(&sm, R, accb, bid - 251);
    ++phC;
    if (bid < 32) {
        bar_arrive(bb, BAR_C + (bid >> 2));
        bar_wait(bb, BAR_C, 8, phC * 4);
        dev_syrk(&sm, R, R, C, bid);
    }
    ++phC;
    if (bid < 32) {
        bar_arrive(bb, BAR_C + (bid >> 2));
        bar_wait(bb, BAR_C, 8, phC * 4);
        dev_cholTrsm(&sm, C, R, Qt, bid);
    }
    ++phE;
    if (bid < 32) bar_arrive(bb, BAR_E + (bid >> 2));
    bar_wait(bb, BAR_E, 8, phE * 4);

    for (int it = 0; it < 50; ++it) {
        dev_gemmG(&sm, Qt, G, Rpart, bid);
        // zero Y (all blocks) and C (blocks 0-31) for this iteration's consumers
        ast2(&Y[bid * 512 + tid * 2], 0.f, 0.f);
        if (bid < 32) ast2(&C[bid * 512 + tid * 2], 0.f, 0.f);
        ++phA;
        bar_arrive(bb, BAR_A + (bid & 63));
        bar_wait(bb, BAR_A, 64, phA * 4);
        {
            float rth, delta;
            dev_ri(&sm, Rpart, &rth, &delta);
            dev_gemmY(&sm, Qt, G, rth, delta, Y, bid);
        }
        ++phB;
        bar_arrive(bb, BAR_B + (bid & 63));
        if (bid < 32) {
            bar_wait(bb, BAR_B, 64, phB * 4);
            dev_syrk(&sm, Y, Y, C, bid);
        }
        ++phC;
        if (bid < 32) {
            bar_arrive(bb, BAR_C + (bid >> 2));
            bar_wait(bb, BAR_C, 8, phC * 4);
            dev_cholTrsm(&sm, C, Y, Qt, bid);
        }
        ++phE;
        if (bid < 32) bar_arrive(bb, BAR_E + (bid >> 2));
        bar_wait(bb, BAR_E, 8, phE * 4);
    }

    dev_trB(&sm, Qt, G, Rpart, accb, bid);
    ++phA;
    bar_arrive(bb, BAR_A + (bid & 63));
    if (bid == 0) {
        bar_wait(bb, BAR_A, 64, phA * 4);
        if (tid == 0)
            out[0] = ald(&accb[0]) / 4194304.f + beta[0] * (ald(&accb[1]) / 2176.f)
                   + (ald(&accb[2]) + ald(&accb[3])) / 131072.f;
    }
}

extern "C" void kernel_launch(void* const* d_in, const int* in_sizes, int n_in,
                              void* d_out, int out_size, void* d_ws, size_t ws_size,
                              hipStream_t stream) {
    const float* t1 = (const float*)d_in[0];
    const float* t2 = (const float*)d_in[1];
    const float* params = (const float*)d_in[2];
    const float* tmin = (const float*)d_in[3];
    const float* tmax = (const float*)d_in[4];
    const float* beta = (const float*)d_in[5];
    const float* R = (const float*)d_in[6];
    float* ws = (float*)d_ws;
    float* out = (float*)d_out;

    // zero accumulators + barrier counter lines (144 lines * 64B + 64B acc)
    hipMemsetAsync(ws + OFF_ACC, 0, 9280, stream);
    mega<<<NBLK, 256, 0, stream>>>(t1, t2, params, tmin, tmax, beta, R, ws, out);
}